// Round 2
// baseline (15066.745 us; speedup 1.0000x reference)
//
#include <hip/hip_runtime.h>
#include <math.h>

#define T_STEPS 512
#define TAPE_N  30
#define LSTRIDE 4194304   // 4096*1024

__device__ __forceinline__ float sigf(float x) { return 1.0f / (1.0f + expf(-x)); }

// ---------------------------------------------------------------------------
// Generic GEMM: Out[m*ldo + n] = sum_k A[n*1024 + k] * X[m*ldx + k] (+ b1 + b2)
// ---------------------------------------------------------------------------
__global__ __launch_bounds__(256) void gemm_nt(
    const float* __restrict__ A, const float* __restrict__ X, float* __restrict__ Out,
    const float* __restrict__ b1, const float* __restrict__ b2,
    int M, int ldx, int ldo)
{
  __shared__ float As[64][65];
  __shared__ float Xs[64][65];
  const int tid = threadIdx.x;
  const int tn = tid & 15, tm = tid >> 4;
  const int bn = blockIdx.x * 64, bm = blockIdx.y * 64;
  float acc[4][4];
  #pragma unroll
  for (int i = 0; i < 4; ++i)
    #pragma unroll
    for (int j = 0; j < 4; ++j) acc[i][j] = 0.f;

  for (int k0 = 0; k0 < 1024; k0 += 64) {
    #pragma unroll
    for (int r = 0; r < 4; ++r) {
      int linear = r * 1024 + tid * 4;
      int nn = linear >> 6, kk = linear & 63;
      float4 av = *(const float4*)(A + (size_t)(bn + nn) * 1024 + k0 + kk);
      As[nn][kk+0] = av.x; As[nn][kk+1] = av.y; As[nn][kk+2] = av.z; As[nn][kk+3] = av.w;
      float4 xv = make_float4(0.f, 0.f, 0.f, 0.f);
      if (bm + nn < M) xv = *(const float4*)(X + (size_t)(bm + nn) * ldx + k0 + kk);
      Xs[nn][kk+0] = xv.x; Xs[nn][kk+1] = xv.y; Xs[nn][kk+2] = xv.z; Xs[nn][kk+3] = xv.w;
    }
    __syncthreads();
    #pragma unroll 16
    for (int kk = 0; kk < 64; ++kk) {
      float av[4], xv[4];
      #pragma unroll
      for (int u = 0; u < 4; ++u) { av[u] = As[tn*4+u][kk]; xv[u] = Xs[tm*4+u][kk]; }
      #pragma unroll
      for (int i = 0; i < 4; ++i)
        #pragma unroll
        for (int j = 0; j < 4; ++j) acc[i][j] += xv[i] * av[j];
    }
    __syncthreads();
  }
  #pragma unroll
  for (int i = 0; i < 4; ++i) {
    int m = bm + tm * 4 + i;
    if (m >= M) continue;
    #pragma unroll
    for (int j = 0; j < 4; ++j) {
      int n = bn + tn * 4 + j;
      float r = acc[i][j];
      if (b1) r += b1[n];
      if (b2) r += b2[n];
      Out[(size_t)m * ldo + n] = r;
    }
  }
}

__global__ void diag_k(const float* __restrict__ wh, const float* __restrict__ wht,
                       float* __restrict__ diag)
{
  int i = blockIdx.x * 256 + threadIdx.x;
  if (i < 2048) {
    int l = i >> 10, h = i & 1023;
    size_t idx = (size_t)l * 1048576 + (size_t)h * 1025;
    diag[i]        = wh[idx];
    diag[2048 + i] = wht[idx];
  }
}

__global__ __launch_bounds__(256) void phase1_l0_k(const float* __restrict__ XI0,
    float* __restrict__ tapeh, float* __restrict__ tapec, float* __restrict__ h0p1)
{
  int t = blockIdx.x;
  #pragma unroll
  for (int r = 0; r < 4; ++r) {
    int c = threadIdx.x + r * 256;
    float gi = XI0[t*4096 + c];
    float gg = XI0[t*4096 + 2048 + c];
    float go = XI0[t*4096 + 3072 + c];
    float cc = sigf(gi) * tanhf(gg);
    float hh = sigf(go) * tanhf(cc);
    tapeh[t*2048 + c] = hh;
    tapec[t*2048 + c] = cc;
    h0p1[t*1024 + c] = hh;
  }
}

__global__ __launch_bounds__(256) void phase1_l1_k(const float* __restrict__ G1,
    float* __restrict__ tapeh, float* __restrict__ tapec)
{
  int t = blockIdx.x;
  #pragma unroll
  for (int r = 0; r < 4; ++r) {
    int c = threadIdx.x + r * 256;
    float gi = G1[t*4096 + c];
    float gg = G1[t*4096 + 2048 + c];
    float go = G1[t*4096 + 3072 + c];
    float cc = sigf(gi) * tanhf(gg);
    float hh = sigf(go) * tanhf(cc);
    tapeh[t*2048 + 1024 + c] = hh;
    tapec[t*2048 + 1024 + c] = cc;
  }
}

// ---------------------------------------------------------------------------
// Grid barrier: 2-level (16 groups x 16 WGs), monotonic epochs, agent scope.
// ---------------------------------------------------------------------------
__device__ __forceinline__ void gbar(unsigned* bar, unsigned ep) {
  __syncthreads();
  if (threadIdx.x == 0) {
    __threadfence();
    unsigned a = __hip_atomic_fetch_add(&bar[64 + (blockIdx.x >> 4) * 32], 1u,
                                        __ATOMIC_RELAXED, __HIP_MEMORY_SCOPE_AGENT);
    if ((a & 15u) == 15u) {
      unsigned r = __hip_atomic_fetch_add(&bar[0], 1u,
                                          __ATOMIC_RELAXED, __HIP_MEMORY_SCOPE_AGENT);
      if ((r & 15u) == 15u)
        __hip_atomic_store(&bar[32], ep, __ATOMIC_RELAXED, __HIP_MEMORY_SCOPE_AGENT);
    }
    while (__hip_atomic_load(&bar[32], __ATOMIC_RELAXED, __HIP_MEMORY_SCOPE_AGENT) < ep)
      __builtin_amdgcn_s_sleep(1);
    __threadfence();
  }
  __syncthreads();
}

__device__ __forceinline__ float red32(float p) {
  #pragma unroll
  for (int o = 16; o >= 1; o >>= 1) p += __shfl_xor(p, o, 64);
  return p;  // sum over the 32-lane half containing this lane
}

__device__ __forceinline__ float red512(float p, float* sred) {
  const int tid = threadIdx.x;
  #pragma unroll
  for (int o = 32; o >= 1; o >>= 1) p += __shfl_xor(p, o, 64);
  if ((tid & 63) == 0) sred[tid >> 6] = p;
  __syncthreads();
  float r = sred[0] + sred[1] + sred[2] + sred[3] + sred[4] + sred[5] + sred[6] + sred[7];
  __syncthreads();
  return r;  // valid in all threads
}

// ---------------------------------------------------------------------------
// Persistent cooperative scan kernel: t = 30..511, 2 barriers/step.
// 256 WGs x 512 threads. WG w owns output cells j in [4w, 4w+4) and gate rows
// {1024*g + 4w + jj}. Weight rows for w_ih1/w_hh0/w_hh1 live in registers.
// ---------------------------------------------------------------------------
__global__ __launch_bounds__(512, 2) void scan_fused(
    const float* __restrict__ wih1, const float* __restrict__ whh,
    const float* __restrict__ bih1, const float* __restrict__ bhh1,
    const float* __restrict__ diag, const float* __restrict__ av,
    const float* __restrict__ XI0, const float* __restrict__ XA,
    float* __restrict__ tapeh, const float* __restrict__ tapecG,
    const float* __restrict__ P0g, const float* __restrict__ P1g,
    float* __restrict__ scoresG, float* __restrict__ prevh,
    float* __restrict__ h0cur, float* __restrict__ h1cur,
    float* __restrict__ outp, unsigned* __restrict__ bar)
{
  const int wg = blockIdx.x, tid = threadIdx.x;
  const int rid = tid >> 5, sub = tid & 31;
  const int row = ((rid & 12) << 8) + (wg << 2) + (rid & 3);  // 1024*(rid/4)+4*wg+(rid%4)

  __shared__ float hbuf[1024];          // transposed: element k at [(k&31)*32 + (k>>5)]
  __shared__ float Pl0[30 * 17], Pl1[30 * 17];
  __shared__ float tc[30 * 9];          // [s*9 + lay*4 + jj]
  __shared__ float sc[64], a0[30], a1[30], mx2[2], iv2[2];
  __shared__ float gls[16], u1s[16], ncs[8], bsum[16];
  __shared__ float h0l[4], c0l[4];
  __shared__ float sred[8];

  // ---- one-time: weights into registers, P/tc into LDS ----
  float wih1r[32], whh0r[32], whh1r[32];
  {
    const float* p1 = wih1 + (size_t)row * 1024 + sub * 32;
    const float* p2 = whh  + (size_t)row * 1024 + sub * 32;
    const float* p3 = whh  + LSTRIDE + (size_t)row * 1024 + sub * 32;
    #pragma unroll
    for (int i = 0; i < 8; ++i) {
      float4 v1 = ((const float4*)p1)[i];
      wih1r[4*i+0]=v1.x; wih1r[4*i+1]=v1.y; wih1r[4*i+2]=v1.z; wih1r[4*i+3]=v1.w;
      float4 v2 = ((const float4*)p2)[i];
      whh0r[4*i+0]=v2.x; whh0r[4*i+1]=v2.y; whh0r[4*i+2]=v2.z; whh0r[4*i+3]=v2.w;
      float4 v3 = ((const float4*)p3)[i];
      whh1r[4*i+0]=v3.x; whh1r[4*i+1]=v3.y; whh1r[4*i+2]=v3.z; whh1r[4*i+3]=v3.w;
    }
  }
  if (sub == 0) bsum[rid] = bih1[row] + bhh1[row];
  for (int k = tid; k < 480; k += 512) {
    int s = k >> 4, r = k & 15;
    int rr = ((r & 12) << 8) + (wg << 2) + (r & 3);
    Pl0[s * 17 + r] = P0g[s * 4096 + rr];
    Pl1[s * 17 + r] = P1g[s * 4096 + rr];
  }
  for (int k = tid; k < 240; k += 512) {
    int s = k >> 3, c = k & 7;
    tc[s * 9 + c] = tapecG[s * 2048 + ((c >> 2) << 10) + (wg << 2) + (c & 3)];
  }
  __syncthreads();

  unsigned ep = 0;

  // ---- bootstrap: scores(30) for all 30 slots, prev_h = 0 ----
  if (wg < 60) {
    int l = wg / 30, s = wg - l * 30;
    const float* dwh = diag + l * 1024;
    float part = 0.f;
    #pragma unroll
    for (int q = 0; q < 2; ++q) {
      int h = tid * 2 + q;
      float th = tapeh[s * 2048 + l * 1024 + h];
      float aa = tanhf(dwh[h] * th + XA[(size_t)30 * 2048 + l * 1024 + h]);
      part += aa * av[l * 1024 + h];
    }
    float tot = red512(part, sred);
    if (tid == 0) scoresG[l * 30 + s] = tot;
  }
  gbar(bar, ++ep);

  for (int t = 30; t < 512; ++t) {
    const int tmod = t % 30;
    const int pslot = (t + 29) % 30;
    // ================= phase X =================
    if (tid < 60) sc[tid] = scoresG[(t & 1) * 64 + tid];
    if (t > 30) {
      // h1(t-1) -> hbuf (transposed)
      for (int k = tid; k < 1024; k += 512) hbuf[((k & 31) << 5) | (k >> 5)] = h1cur[k];
      // redundant new-slot scores (slot pslot), both layers
      float np0 = 0.f, np1 = 0.f;
      #pragma unroll 1
      for (int q = 0; q < 2; ++q) {
        int h = tid * 2 + q;
        {
          float th = tapeh[pslot * 2048 + h];
          float ph = prevh[((t - 1) & 1) * 2048 + h];
          float aa = tanhf(diag[h] * th + XA[(size_t)t * 2048 + h] + diag[2048 + h] * ph);
          np0 += aa * av[h];
        }
        {
          float th = tapeh[pslot * 2048 + 1024 + h];
          float ph = prevh[((t - 1) & 1) * 2048 + 1024 + h];
          float aa = tanhf(diag[1024 + h] * th + XA[(size_t)t * 2048 + 1024 + h] +
                           diag[3072 + h] * ph);
          np1 += aa * av[1024 + h];
        }
      }
      float r0 = red512(np0, sred);
      float r1 = red512(np1, sred);
      if (tid == 0) { sc[pslot] = r0; sc[30 + pslot] = r1; }
      __syncthreads();
      // P1 column update for pslot (owner-local, into LDS)
      float pc = 0.f;
      #pragma unroll
      for (int i = 0; i < 32; ++i) pc += whh1r[i] * hbuf[(i << 5) + sub];
      pc = red32(pc);
      if (sub == 0) Pl1[pslot * 17 + rid] = pc;
      __syncthreads();
    } else {
      __syncthreads();
    }
    // softmax over tape dim, both layers
    if (tid < 2) {
      float m = -1e30f;
      #pragma unroll
      for (int s = 0; s < 30; ++s) m = fmaxf(m, sc[tid * 30 + s]);
      mx2[tid] = m;
    }
    __syncthreads();
    if (tid < 60) {
      int l = tid / 30;
      float e = expf(sc[tid] - mx2[l]);
      (l ? a1 : a0)[tid - l * 30] = e;
    }
    __syncthreads();
    if (tid < 2) {
      float s = 0.f;
      #pragma unroll
      for (int i = 0; i < 30; ++i) s += (tid ? a1 : a0)[i];
      iv2[tid] = 1.f / s;
    }
    __syncthreads();
    if (tid < 60) { int l = tid / 30; (l ? a1 : a0)[tid - l * 30] *= iv2[l]; }
    __syncthreads();
    // gates0 (XI0 + sum_s a0 P0), u1 (sum_s a1 P1), weighted c-tape sums
    {
      float p = (sub < 30) ? a0[sub] * Pl0[sub * 17 + rid] : 0.f;
      p = red32(p);
      if (sub == 0) gls[rid] = p + XI0[(size_t)t * 4096 + row];
      float pu = (sub < 30) ? a1[sub] * Pl1[sub * 17 + rid] : 0.f;
      pu = red32(pu);
      if (sub == 0) u1s[rid] = pu;
      float pn = 0.f;
      if (rid < 8 && sub < 30)
        pn = (rid < 4 ? a0[sub] : a1[sub]) * tc[sub * 9 + (rid & 4) + (rid & 3)];
      pn = red32(pn);
      if (rid < 8 && sub == 0) ncs[rid] = pn;
    }
    __syncthreads();
    if (tid < 4) {
      float gi = gls[tid], gf = gls[4 + tid], gg = gls[8 + tid], go = gls[12 + tid];
      float c0 = sigf(gf) * ncs[tid] + sigf(gi) * tanhf(gg);
      float h0 = sigf(go) * tanhf(c0);
      h0l[tid] = h0; c0l[tid] = c0;
      h0cur[(wg << 2) + tid] = h0;
    }
    // old-slot scores for step t+1 (58 WGs), + prevh (new_h) publication
    if (wg < 58 && t < 511) {
      int l = wg / 29, ii = wg - l * 29;
      int ss = tmod + 1 + ii; if (ss >= 30) ss -= 30;
      const float* aL = l ? a1 : a0;
      const float* dwh = diag + l * 1024;
      const float* dwht = diag + 2048 + l * 1024;
      float part = 0.f;
      #pragma unroll 1
      for (int q = 0; q < 2; ++q) {
        int h = tid * 2 + q;
        float acc = 0.f;
        #pragma unroll
        for (int s = 0; s < 30; ++s) acc += aL[s] * tapeh[s * 2048 + l * 1024 + h];
        if (wg == 0 || wg == 29) prevh[(t & 1) * 2048 + l * 1024 + h] = acc;
        float th = tapeh[ss * 2048 + l * 1024 + h];
        float aa = tanhf(dwh[h] * th + XA[(size_t)(t + 1) * 2048 + l * 1024 + h] + dwht[h] * acc);
        part += aa * av[l * 1024 + h];
      }
      float tot = red512(part, sred);
      if (tid == 0) scoresG[((t + 1) & 1) * 64 + l * 30 + ss] = tot;
    }
    gbar(bar, ++ep);
    // ================= phase Y =================
    for (int k = tid; k < 1024; k += 512) hbuf[((k & 31) << 5) | (k >> 5)] = h0cur[k];
    __syncthreads();
    {
      float m1 = 0.f;
      #pragma unroll
      for (int i = 0; i < 32; ++i) m1 += wih1r[i] * hbuf[(i << 5) + sub];
      m1 = red32(m1);
      if (sub == 0) gls[rid] = m1 + u1s[rid] + bsum[rid];
      float pc0 = 0.f;
      #pragma unroll
      for (int i = 0; i < 32; ++i) pc0 += whh0r[i] * hbuf[(i << 5) + sub];
      pc0 = red32(pc0);
      if (sub == 0) Pl0[tmod * 17 + rid] = pc0;
    }
    __syncthreads();
    if (tid < 4) {
      int j = (wg << 2) + tid;
      float gi = gls[tid], gf = gls[4 + tid], gg = gls[8 + tid], go = gls[12 + tid];
      float c1 = sigf(gf) * ncs[4 + tid] + sigf(gi) * tanhf(gg);
      float h1 = sigf(go) * tanhf(c1);
      outp[(size_t)(t - TAPE_N) * 1024 + j] = h1;
      h1cur[j] = h1;
      tapeh[tmod * 2048 + j] = h0l[tid];
      tapeh[tmod * 2048 + 1024 + j] = h1;
      tc[tmod * 9 + tid] = c0l[tid];
      tc[tmod * 9 + 4 + tid] = c1;
    }
    if (t == 511) break;
    gbar(bar, ++ep);
  }
}

// ---------------------------------------------------------------------------
extern "C" void kernel_launch(void* const* d_in, const int* in_sizes, int n_in,
                              void* d_out, int out_size, void* d_ws, size_t ws_size,
                              hipStream_t stream) {
  (void)in_sizes; (void)n_in; (void)out_size; (void)ws_size;
  const float* xs    = (const float*)d_in[0];
  const float* w_ih  = (const float*)d_in[1];
  const float* w_hh  = (const float*)d_in[2];
  const float* b_ih  = (const float*)d_in[3];
  const float* b_hh  = (const float*)d_in[4];
  const float* a_wh  = (const float*)d_in[5];
  const float* a_wx  = (const float*)d_in[6];
  const float* a_wht = (const float*)d_in[7];
  const float* a_v   = (const float*)d_in[8];
  float* outp = (float*)d_out;

  float* ws    = (float*)d_ws;
  float* XI0   = ws;                      // 512*4096
  float* XA    = XI0   + 512 * 4096;      // 512*2048
  float* tapeh = XA    + 512 * 2048;      // 30*2048
  float* tapec = tapeh + 30 * 2048;       // 30*2048
  float* P0g   = tapec + 30 * 2048;       // 30*4096
  float* P1g   = P0g   + 30 * 4096;       // 30*4096
  float* diag  = P1g   + 30 * 4096;       // 4096
  float* scor  = diag  + 4096;            // 2*64
  float* prevh = scor  + 128;             // 2*2048
  float* h0cur = prevh + 4096;            // 1024
  float* h1cur = h0cur + 1024;            // 1024
  float* h0p1  = h1cur + 1024;            // 30*1024
  float* G1b   = h0p1  + 30 * 1024;       // 30*4096
  unsigned* bar = (unsigned*)(G1b + 30 * 4096);  // 1024 uints

  hipMemsetAsync(outp + (size_t)482 * 1024, 0, 30 * 1024 * sizeof(float), stream);
  hipMemsetAsync(bar, 0, 4096, stream);

  diag_k<<<8, 256, 0, stream>>>(a_wh, a_wht, diag);

  gemm_nt<<<dim3(64, 8), 256, 0, stream>>>(w_ih, xs, XI0, b_ih, b_hh, 512, 1024, 4096);
  gemm_nt<<<dim3(16, 8), 256, 0, stream>>>(a_wx, xs, XA, nullptr, nullptr, 512, 1024, 2048);
  gemm_nt<<<dim3(16, 8), 256, 0, stream>>>(a_wx + LSTRIDE / 4, xs, XA + 1024, nullptr, nullptr, 512, 1024, 2048);

  phase1_l0_k<<<30, 256, 0, stream>>>(XI0, tapeh, tapec, h0p1);
  gemm_nt<<<dim3(64, 1), 256, 0, stream>>>(w_ih + LSTRIDE, h0p1, G1b, b_ih + 4096, b_hh + 4096, 30, 1024, 4096);
  phase1_l1_k<<<30, 256, 0, stream>>>(G1b, tapeh, tapec);

  gemm_nt<<<dim3(64, 1), 256, 0, stream>>>(w_hh, tapeh, P0g, nullptr, nullptr, 30, 2048, 4096);
  gemm_nt<<<dim3(64, 1), 256, 0, stream>>>(w_hh + LSTRIDE, tapeh + 1024, P1g, nullptr, nullptr, 30, 2048, 4096);

  const float* wih1p = w_ih + LSTRIDE;
  const float* whhp  = w_hh;
  const float* bih1p = b_ih + 4096;
  const float* bhh1p = b_hh + 4096;
  void* kargs[] = {
    (void*)&wih1p, (void*)&whhp, (void*)&bih1p, (void*)&bhh1p,
    (void*)&diag,  (void*)&a_v,  (void*)&XI0,   (void*)&XA,
    (void*)&tapeh, (void*)&tapec, (void*)&P0g,  (void*)&P1g,
    (void*)&scor,  (void*)&prevh, (void*)&h0cur, (void*)&h1cur,
    (void*)&outp,  (void*)&bar
  };
  hipLaunchCooperativeKernel((void*)scan_fused, dim3(256), dim3(512), kargs, 0, stream);
}

// Round 3
// 8580.599 us; speedup vs baseline: 1.7559x; 1.7559x over previous
//
#include <hip/hip_runtime.h>
#include <math.h>

#define T_STEPS 512
#define TAPE_N  30
#define LSTRIDE 4194304   // 4096*1024

__device__ __forceinline__ float sigf(float x) { return 1.0f / (1.0f + expf(-x)); }

// Coherent (XCD-L2-bypassing) scalar access for cross-WG data. No fences needed
// anywhere because ALL cross-WG traffic goes through these.
__device__ __forceinline__ float cload(const float* p) {
  return __hip_atomic_load(p, __ATOMIC_RELAXED, __HIP_MEMORY_SCOPE_AGENT);
}
__device__ __forceinline__ void cstore(float* p, float v) {
  __hip_atomic_store(p, v, __ATOMIC_RELAXED, __HIP_MEMORY_SCOPE_AGENT);
}

// ---------------------------------------------------------------------------
// Generic GEMM: Out[m*ldo + n] = sum_k A[n*1024 + k] * X[m*ldx + k] (+ b1 + b2)
// ---------------------------------------------------------------------------
__global__ __launch_bounds__(256) void gemm_nt(
    const float* __restrict__ A, const float* __restrict__ X, float* __restrict__ Out,
    const float* __restrict__ b1, const float* __restrict__ b2,
    int M, int ldx, int ldo)
{
  __shared__ float As[64][65];
  __shared__ float Xs[64][65];
  const int tid = threadIdx.x;
  const int tn = tid & 15, tm = tid >> 4;
  const int bn = blockIdx.x * 64, bm = blockIdx.y * 64;
  float acc[4][4];
  #pragma unroll
  for (int i = 0; i < 4; ++i)
    #pragma unroll
    for (int j = 0; j < 4; ++j) acc[i][j] = 0.f;

  for (int k0 = 0; k0 < 1024; k0 += 64) {
    #pragma unroll
    for (int r = 0; r < 4; ++r) {
      int linear = r * 1024 + tid * 4;
      int nn = linear >> 6, kk = linear & 63;
      float4 av = *(const float4*)(A + (size_t)(bn + nn) * 1024 + k0 + kk);
      As[nn][kk+0] = av.x; As[nn][kk+1] = av.y; As[nn][kk+2] = av.z; As[nn][kk+3] = av.w;
      float4 xv = make_float4(0.f, 0.f, 0.f, 0.f);
      if (bm + nn < M) xv = *(const float4*)(X + (size_t)(bm + nn) * ldx + k0 + kk);
      Xs[nn][kk+0] = xv.x; Xs[nn][kk+1] = xv.y; Xs[nn][kk+2] = xv.z; Xs[nn][kk+3] = xv.w;
    }
    __syncthreads();
    #pragma unroll 16
    for (int kk = 0; kk < 64; ++kk) {
      float av[4], xv[4];
      #pragma unroll
      for (int u = 0; u < 4; ++u) { av[u] = As[tn*4+u][kk]; xv[u] = Xs[tm*4+u][kk]; }
      #pragma unroll
      for (int i = 0; i < 4; ++i)
        #pragma unroll
        for (int j = 0; j < 4; ++j) acc[i][j] += xv[i] * av[j];
    }
    __syncthreads();
  }
  #pragma unroll
  for (int i = 0; i < 4; ++i) {
    int m = bm + tm * 4 + i;
    if (m >= M) continue;
    #pragma unroll
    for (int j = 0; j < 4; ++j) {
      int n = bn + tn * 4 + j;
      float r = acc[i][j];
      if (b1) r += b1[n];
      if (b2) r += b2[n];
      Out[(size_t)m * ldo + n] = r;
    }
  }
}

__global__ void diag_k(const float* __restrict__ wh, const float* __restrict__ wht,
                       float* __restrict__ diag)
{
  int i = blockIdx.x * 256 + threadIdx.x;
  if (i < 2048) {
    int l = i >> 10, h = i & 1023;
    size_t idx = (size_t)l * 1048576 + (size_t)h * 1025;
    diag[i]        = wh[idx];
    diag[2048 + i] = wht[idx];
  }
}

__global__ __launch_bounds__(256) void phase1_l0_k(const float* __restrict__ XI0,
    float* __restrict__ tapeh, float* __restrict__ tapec, float* __restrict__ h0p1)
{
  int t = blockIdx.x;
  #pragma unroll
  for (int r = 0; r < 4; ++r) {
    int c = threadIdx.x + r * 256;
    float gi = XI0[t*4096 + c];
    float gg = XI0[t*4096 + 2048 + c];
    float go = XI0[t*4096 + 3072 + c];
    float cc = sigf(gi) * tanhf(gg);
    float hh = sigf(go) * tanhf(cc);
    tapeh[t*2048 + c] = hh;
    tapec[t*2048 + c] = cc;
    h0p1[t*1024 + c] = hh;
  }
}

__global__ __launch_bounds__(256) void phase1_l1_k(const float* __restrict__ G1,
    float* __restrict__ tapeh, float* __restrict__ tapec)
{
  int t = blockIdx.x;
  #pragma unroll
  for (int r = 0; r < 4; ++r) {
    int c = threadIdx.x + r * 256;
    float gi = G1[t*4096 + c];
    float gg = G1[t*4096 + 2048 + c];
    float go = G1[t*4096 + 3072 + c];
    float cc = sigf(gi) * tanhf(gg);
    float hh = sigf(go) * tanhf(cc);
    tapeh[t*2048 + 1024 + c] = hh;
    tapec[t*2048 + 1024 + c] = cc;
  }
}

// ---------------------------------------------------------------------------
// Fence-free grid sync: per-WG epoch slots, wave-0 distributed polling.
// Correctness: all cross-WG data uses cload/cstore (coherence-point ops);
// vmcnt(0) drains this wave's stores before the slot publish.
// ---------------------------------------------------------------------------
__device__ __forceinline__ void gsync(unsigned* __restrict__ bar, unsigned ep) {
  asm volatile("s_waitcnt vmcnt(0)" ::: "memory");
  __syncthreads();
  const int tid = threadIdx.x;
  if (tid == 0)
    __hip_atomic_store(&bar[blockIdx.x], ep, __ATOMIC_RELAXED, __HIP_MEMORY_SCOPE_AGENT);
  if (tid < 64) {
    for (;;) {
      unsigned v0 = __hip_atomic_load(&bar[tid],       __ATOMIC_RELAXED, __HIP_MEMORY_SCOPE_AGENT);
      unsigned v1 = __hip_atomic_load(&bar[tid + 64],  __ATOMIC_RELAXED, __HIP_MEMORY_SCOPE_AGENT);
      unsigned v2 = __hip_atomic_load(&bar[tid + 128], __ATOMIC_RELAXED, __HIP_MEMORY_SCOPE_AGENT);
      unsigned v3 = __hip_atomic_load(&bar[tid + 192], __ATOMIC_RELAXED, __HIP_MEMORY_SCOPE_AGENT);
      unsigned mn = min(min(v0, v1), min(v2, v3));
      if (__all((int)(mn >= ep))) break;
      __builtin_amdgcn_s_sleep(1);
    }
  }
  __syncthreads();
  asm volatile("" ::: "memory");
}

__device__ __forceinline__ float red32(float p) {
  #pragma unroll
  for (int o = 16; o >= 1; o >>= 1) p += __shfl_xor(p, o, 64);
  return p;  // per-32-lane-half sum
}

__device__ __forceinline__ float red512(float p, float* sred) {
  const int tid = threadIdx.x;
  #pragma unroll
  for (int o = 32; o >= 1; o >>= 1) p += __shfl_xor(p, o, 64);
  if ((tid & 63) == 0) sred[tid >> 6] = p;
  __syncthreads();
  float r = sred[0] + sred[1] + sred[2] + sred[3] + sred[4] + sred[5] + sred[6] + sred[7];
  __syncthreads();
  return r;
}

// ---------------------------------------------------------------------------
// Persistent cooperative scan: 256 WGs x 512 thr, 2 fence-free syncs/step.
// WG w owns cells [4w,4w+4); 16 gate rows x 3 matrices in registers.
// WGs 0..57 additionally keep a 30x1024 LDS copy of their layer's h-tape.
// ---------------------------------------------------------------------------
__global__ __launch_bounds__(512, 2) void scan_fused(
    const float* __restrict__ wih1, const float* __restrict__ whh,
    const float* __restrict__ bih1, const float* __restrict__ bhh1,
    const float* __restrict__ diag, const float* __restrict__ av,
    const float* __restrict__ XI0, const float* __restrict__ XA,
    const float* __restrict__ tapehG, const float* __restrict__ tapecG,
    const float* __restrict__ P0g, const float* __restrict__ P1g,
    float* __restrict__ scoresG, float* __restrict__ prevh,
    float* __restrict__ h0cur, float* __restrict__ h1cur,
    float* __restrict__ outp, unsigned* __restrict__ bar)
{
  const int wg = blockIdx.x, tid = threadIdx.x;
  const int rid = tid >> 5, sub = tid & 31;
  const int row = ((rid & 12) << 8) + (wg << 2) + (rid & 3);
  const bool isScore = (wg < 58);
  const int lw = (wg < 29) ? 0 : 1;
  const int ii = (wg < 29) ? wg : wg - 29;

  __shared__ float tape[30 * 1024];      // score WGs: layer-lw h-tape
  __shared__ float hbuf[33 * 32];        // padded transpose buffer
  __shared__ float Pl0[30 * 17], Pl1[30 * 17];
  __shared__ float tcs[30 * 9];
  __shared__ float sc[64];
  __shared__ float a0[32], a1[32];
  __shared__ float gls[16], u1s[16], ncs[8], bsum[16], c0l[4];
  __shared__ float sred[8];

  // ---- one-time init ----
  float wih1r[32], whh0r[32], whh1r[32];
  {
    const float* p1 = wih1 + (size_t)row * 1024 + sub * 32;
    const float* p2 = whh  + (size_t)row * 1024 + sub * 32;
    const float* p3 = whh  + LSTRIDE + (size_t)row * 1024 + sub * 32;
    #pragma unroll
    for (int i = 0; i < 8; ++i) {
      float4 v1 = ((const float4*)p1)[i];
      wih1r[4*i+0]=v1.x; wih1r[4*i+1]=v1.y; wih1r[4*i+2]=v1.z; wih1r[4*i+3]=v1.w;
      float4 v2 = ((const float4*)p2)[i];
      whh0r[4*i+0]=v2.x; whh0r[4*i+1]=v2.y; whh0r[4*i+2]=v2.z; whh0r[4*i+3]=v2.w;
      float4 v3 = ((const float4*)p3)[i];
      whh1r[4*i+0]=v3.x; whh1r[4*i+1]=v3.y; whh1r[4*i+2]=v3.z; whh1r[4*i+3]=v3.w;
    }
  }
  if (sub == 0) bsum[rid] = bih1[row] + bhh1[row];
  for (int k = tid; k < 480; k += 512) {
    int s = k >> 4, r = k & 15;
    int rr = ((r & 12) << 8) + (wg << 2) + (r & 3);
    Pl0[s * 17 + r] = P0g[s * 4096 + rr];
    Pl1[s * 17 + r] = P1g[s * 4096 + rr];
  }
  for (int k = tid; k < 240; k += 512) {
    int s = k >> 3, c = k & 7;
    tcs[s * 9 + c] = tapecG[s * 2048 + ((c >> 2) << 10) + (wg << 2) + (c & 3)];
  }
  if (isScore) {
    for (int k = tid; k < 7680; k += 512) {
      int s = k >> 8, off = (k & 255) << 2;
      *(float4*)&tape[s * 1024 + off] =
          *(const float4*)&tapehG[s * 2048 + lw * 1024 + off];
    }
  }
  __syncthreads();

  unsigned ep = 0;

  // ---- bootstrap scores for t=30 (prev_h = 0) ----
  if (isScore) {
    for (int s = ii; s < 30; s += 29) {
      float part = 0.f;
      #pragma unroll
      for (int q = 0; q < 2; ++q) {
        int h = tid * 2 + q;
        float aa = tanhf(diag[lw*1024 + h] * tape[s*1024 + h]
                         + XA[(size_t)30 * 2048 + lw*1024 + h]);
        part += aa * av[lw*1024 + h];
      }
      float tot = red512(part, sred);
      if (tid == 0) cstore(&scoresG[lw * 30 + s], tot);
    }
  }
  gsync(bar, ++ep);

  for (int t = 30; t < 512; ++t) {
    const int tmod = t % 30;
    const int pslot = (t + 29) % 30;
    const int pp = (t - 1) & 1;
    // ================= phase X =================
    if (tid < 60) sc[tid] = cload(&scoresG[(t & 1) * 64 + tid]);
    if (t > 30) {
      // h1(t-1) -> hbuf (padded transpose)
      {
        float v0 = cload(&h1cur[pp * 1024 + tid]);
        float v1 = cload(&h1cur[pp * 1024 + tid + 512]);
        hbuf[(tid & 31) * 33 + (tid >> 5)] = v0;
        hbuf[(tid & 31) * 33 + (tid >> 5) + 16] = v1;
      }
      // score WGs: refresh LDS tape slot pslot with h_lw(t-1)
      if (isScore) {
        const float* src = (lw ? h1cur : h0cur) + pp * 1024;
        float2 v; v.x = cload(&src[2 * tid]); v.y = cload(&src[2 * tid + 1]);
        *(float2*)&tape[pslot * 1024 + 2 * tid] = v;
      }
      // redundant new-slot scores (all WGs)
      float np0 = 0.f, np1 = 0.f;
      #pragma unroll
      for (int q = 0; q < 2; ++q) {
        int h = tid * 2 + q;
        float th0 = cload(&h0cur[pp * 1024 + h]);
        float ph0 = cload(&prevh[pp * 2048 + h]);
        np0 += av[h] * tanhf(diag[h] * th0 + XA[(size_t)t * 2048 + h] + diag[2048 + h] * ph0);
        float th1 = cload(&h1cur[pp * 1024 + h]);
        float ph1 = cload(&prevh[pp * 2048 + 1024 + h]);
        np1 += av[1024 + h] * tanhf(diag[1024 + h] * th1 + XA[(size_t)t * 2048 + 1024 + h]
                                    + diag[3072 + h] * ph1);
      }
      float r0 = red512(np0, sred);
      float r1 = red512(np1, sred);
      if (tid == 0) { sc[pslot] = r0; sc[30 + pslot] = r1; }
      // P1 column update for pslot (hbuf valid: red512 synced)
      float pc = 0.f;
      #pragma unroll
      for (int i = 0; i < 32; ++i) pc += whh1r[i] * hbuf[i * 33 + sub];
      pc = red32(pc);
      if (sub == 0) Pl1[pslot * 17 + rid] = pc;
    }
    __syncthreads();
    // softmax over tape dim, both layers (wave 0, shuffle reduce)
    if (tid < 64) {
      int l = tid >> 5, s2 = tid & 31;
      float v = (s2 < 30) ? sc[l * 30 + s2] : -1e30f;
      float m = v;
      #pragma unroll
      for (int o = 16; o >= 1; o >>= 1) m = fmaxf(m, __shfl_xor(m, o, 64));
      float e = (s2 < 30) ? expf(v - m) : 0.f;
      float sm = e;
      #pragma unroll
      for (int o = 16; o >= 1; o >>= 1) sm += __shfl_xor(sm, o, 64);
      (l ? a1 : a0)[s2] = e / sm;
    }
    __syncthreads();
    // gates0 / u1 / c-tape sums
    {
      float p = (sub < 30) ? a0[sub] * Pl0[sub * 17 + rid] : 0.f;
      p = red32(p);
      if (sub == 0) gls[rid] = p + XI0[(size_t)t * 4096 + row];
      float pu = (sub < 30) ? a1[sub] * Pl1[sub * 17 + rid] : 0.f;
      pu = red32(pu);
      if (sub == 0) u1s[rid] = pu;
      float pn = 0.f;
      if (rid < 8 && sub < 30)
        pn = (rid < 4 ? a0[sub] : a1[sub]) * tcs[sub * 9 + (rid & 4) + (rid & 3)];
      pn = red32(pn);
      if (rid < 8 && sub == 0) ncs[rid] = pn;
    }
    __syncthreads();
    if (tid < 4) {
      float gi = gls[tid], gf = gls[4 + tid], gg = gls[8 + tid], go = gls[12 + tid];
      float c0 = sigf(gf) * ncs[tid] + sigf(gi) * tanhf(gg);
      float h0 = sigf(go) * tanhf(c0);
      c0l[tid] = c0;
      cstore(&h0cur[(t & 1) * 1024 + (wg << 2) + tid], h0);
    }
    // old-slot scores for t+1 from LDS tape, + prevh (new_h) publication
    if (isScore && t < 511) {
      int ss = tmod + 1 + ii; if (ss >= 30) ss -= 30;
      const float* aL = lw ? a1 : a0;
      float part = 0.f;
      #pragma unroll
      for (int q = 0; q < 2; ++q) {
        int h = tid * 2 + q;
        float acc = 0.f;
        #pragma unroll
        for (int s = 0; s < 30; ++s) acc += aL[s] * tape[s * 1024 + h];
        if (ii == 0) cstore(&prevh[(t & 1) * 2048 + lw * 1024 + h], acc);
        float aa = tanhf(diag[lw*1024 + h] * tape[ss * 1024 + h]
                         + XA[(size_t)(t + 1) * 2048 + lw * 1024 + h]
                         + diag[2048 + lw*1024 + h] * acc);
        part += aa * av[lw*1024 + h];
      }
      float tot = red512(part, sred);
      if (tid == 0) cstore(&scoresG[((t + 1) & 1) * 64 + lw * 30 + ss], tot);
    }
    gsync(bar, ++ep);
    // ================= phase Y =================
    {
      float v0 = cload(&h0cur[(t & 1) * 1024 + tid]);
      float v1 = cload(&h0cur[(t & 1) * 1024 + tid + 512]);
      hbuf[(tid & 31) * 33 + (tid >> 5)] = v0;
      hbuf[(tid & 31) * 33 + (tid >> 5) + 16] = v1;
    }
    __syncthreads();
    {
      float m1 = 0.f, pc0 = 0.f;
      #pragma unroll
      for (int i = 0; i < 32; ++i) {
        float hv = hbuf[i * 33 + sub];
        m1 += wih1r[i] * hv;
        pc0 += whh0r[i] * hv;
      }
      m1 = red32(m1);
      pc0 = red32(pc0);
      if (sub == 0) { gls[rid] = m1 + u1s[rid] + bsum[rid]; Pl0[tmod * 17 + rid] = pc0; }
    }
    __syncthreads();
    if (tid < 4) {
      int j = (wg << 2) + tid;
      float gi = gls[tid], gf = gls[4 + tid], gg = gls[8 + tid], go = gls[12 + tid];
      float c1 = sigf(gf) * ncs[4 + tid] + sigf(gi) * tanhf(gg);
      float h1 = sigf(go) * tanhf(c1);
      outp[(size_t)(t - TAPE_N) * 1024 + j] = h1;
      cstore(&h1cur[(t & 1) * 1024 + j], h1);
      tcs[tmod * 9 + tid] = c0l[tid];
      tcs[tmod * 9 + 4 + tid] = c1;
    }
    if (t == 511) break;
    gsync(bar, ++ep);
  }
}

// ---------------------------------------------------------------------------
extern "C" void kernel_launch(void* const* d_in, const int* in_sizes, int n_in,
                              void* d_out, int out_size, void* d_ws, size_t ws_size,
                              hipStream_t stream) {
  (void)in_sizes; (void)n_in; (void)out_size; (void)ws_size;
  const float* xs    = (const float*)d_in[0];
  const float* w_ih  = (const float*)d_in[1];
  const float* w_hh  = (const float*)d_in[2];
  const float* b_ih  = (const float*)d_in[3];
  const float* b_hh  = (const float*)d_in[4];
  const float* a_wh  = (const float*)d_in[5];
  const float* a_wx  = (const float*)d_in[6];
  const float* a_wht = (const float*)d_in[7];
  const float* a_v   = (const float*)d_in[8];
  float* outp = (float*)d_out;

  float* ws     = (float*)d_ws;
  float* XI0    = ws;                      // 512*4096
  float* XA     = XI0    + 512 * 4096;     // 512*2048
  float* tapehG = XA     + 512 * 2048;     // 30*2048
  float* tapecG = tapehG + 30 * 2048;      // 30*2048
  float* P0g    = tapecG + 30 * 2048;      // 30*4096
  float* P1g    = P0g    + 30 * 4096;      // 30*4096
  float* diag   = P1g    + 30 * 4096;      // 4096
  float* scor   = diag   + 4096;           // 2*64
  float* prevh  = scor   + 128;            // 2*2048
  float* h0cur  = prevh  + 4096;           // 2*1024
  float* h1cur  = h0cur  + 2048;           // 2*1024
  float* h0p1   = h1cur  + 2048;           // 30*1024
  float* G1b    = h0p1   + 30 * 1024;      // 30*4096
  unsigned* bar = (unsigned*)(G1b + 30 * 4096);  // 256 uints

  hipMemsetAsync(outp + (size_t)482 * 1024, 0, 30 * 1024 * sizeof(float), stream);
  hipMemsetAsync(bar, 0, 1024, stream);

  diag_k<<<8, 256, 0, stream>>>(a_wh, a_wht, diag);

  gemm_nt<<<dim3(64, 8), 256, 0, stream>>>(w_ih, xs, XI0, b_ih, b_hh, 512, 1024, 4096);
  gemm_nt<<<dim3(16, 8), 256, 0, stream>>>(a_wx, xs, XA, nullptr, nullptr, 512, 1024, 2048);
  gemm_nt<<<dim3(16, 8), 256, 0, stream>>>(a_wx + LSTRIDE / 4, xs, XA + 1024, nullptr, nullptr, 512, 1024, 2048);

  phase1_l0_k<<<30, 256, 0, stream>>>(XI0, tapehG, tapecG, h0p1);
  gemm_nt<<<dim3(64, 1), 256, 0, stream>>>(w_ih + LSTRIDE, h0p1, G1b, b_ih + 4096, b_hh + 4096, 30, 1024, 4096);
  phase1_l1_k<<<30, 256, 0, stream>>>(G1b, tapehG, tapecG);

  gemm_nt<<<dim3(64, 1), 256, 0, stream>>>(w_hh, tapehG, P0g, nullptr, nullptr, 30, 2048, 4096);
  gemm_nt<<<dim3(64, 1), 256, 0, stream>>>(w_hh + LSTRIDE, tapehG + 1024, P1g, nullptr, nullptr, 30, 2048, 4096);

  const float* wih1p = w_ih + LSTRIDE;
  const float* whhp  = w_hh;
  const float* bih1p = b_ih + 4096;
  const float* bhh1p = b_hh + 4096;
  void* kargs[] = {
    (void*)&wih1p, (void*)&whhp, (void*)&bih1p, (void*)&bhh1p,
    (void*)&diag,  (void*)&a_v,  (void*)&XI0,   (void*)&XA,
    (void*)&tapehG, (void*)&tapecG, (void*)&P0g, (void*)&P1g,
    (void*)&scor,  (void*)&prevh, (void*)&h0cur, (void*)&h1cur,
    (void*)&outp,  (void*)&bar
  };
  hipLaunchCooperativeKernel((void*)scan_fused, dim3(256), dim3(512), kargs, 0, stream);
}

// Round 4
// 5034.576 us; speedup vs baseline: 2.9927x; 1.7043x over previous
//
#include <hip/hip_runtime.h>
#include <math.h>

#define T_STEPS 512
#define TAPE_N  30
#define LSTRIDE 4194304   // 4096*1024

__device__ __forceinline__ float sigf(float x) { return 1.0f / (1.0f + expf(-x)); }

// Coherent (L2-bypassing) access for ALL cross-WG data => no fences needed.
__device__ __forceinline__ float cload(const float* p) {
  return __hip_atomic_load(p, __ATOMIC_RELAXED, __HIP_MEMORY_SCOPE_AGENT);
}
__device__ __forceinline__ void cstore(float* p, float v) {
  __hip_atomic_store(p, v, __ATOMIC_RELAXED, __HIP_MEMORY_SCOPE_AGENT);
}
__device__ __forceinline__ float2 cload2(const float* p) {
  unsigned long long v = __hip_atomic_load((const unsigned long long*)p,
                                           __ATOMIC_RELAXED, __HIP_MEMORY_SCOPE_AGENT);
  float2 r;
  r.x = __uint_as_float((unsigned)v);
  r.y = __uint_as_float((unsigned)(v >> 32));
  return r;
}
__device__ __forceinline__ void cstore2(float* p, float2 v) {
  unsigned long long u = ((unsigned long long)__float_as_uint(v.y) << 32) |
                         (unsigned long long)__float_as_uint(v.x);
  __hip_atomic_store((unsigned long long*)p, u, __ATOMIC_RELAXED, __HIP_MEMORY_SCOPE_AGENT);
}

// ---------------------------------------------------------------------------
// Generic GEMM: Out[m*ldo + n] = sum_k A[n*1024 + k] * X[m*ldx + k] (+ b1 + b2)
// ---------------------------------------------------------------------------
__global__ __launch_bounds__(256) void gemm_nt(
    const float* __restrict__ A, const float* __restrict__ X, float* __restrict__ Out,
    const float* __restrict__ b1, const float* __restrict__ b2,
    int M, int ldx, int ldo)
{
  __shared__ float As[64][65];
  __shared__ float Xs[64][65];
  const int tid = threadIdx.x;
  const int tn = tid & 15, tm = tid >> 4;
  const int bn = blockIdx.x * 64, bm = blockIdx.y * 64;
  float acc[4][4];
  #pragma unroll
  for (int i = 0; i < 4; ++i)
    #pragma unroll
    for (int j = 0; j < 4; ++j) acc[i][j] = 0.f;

  for (int k0 = 0; k0 < 1024; k0 += 64) {
    #pragma unroll
    for (int r = 0; r < 4; ++r) {
      int linear = r * 1024 + tid * 4;
      int nn = linear >> 6, kk = linear & 63;
      float4 av = *(const float4*)(A + (size_t)(bn + nn) * 1024 + k0 + kk);
      As[nn][kk+0] = av.x; As[nn][kk+1] = av.y; As[nn][kk+2] = av.z; As[nn][kk+3] = av.w;
      float4 xv = make_float4(0.f, 0.f, 0.f, 0.f);
      if (bm + nn < M) xv = *(const float4*)(X + (size_t)(bm + nn) * ldx + k0 + kk);
      Xs[nn][kk+0] = xv.x; Xs[nn][kk+1] = xv.y; Xs[nn][kk+2] = xv.z; Xs[nn][kk+3] = xv.w;
    }
    __syncthreads();
    #pragma unroll 16
    for (int kk = 0; kk < 64; ++kk) {
      float av[4], xv[4];
      #pragma unroll
      for (int u = 0; u < 4; ++u) { av[u] = As[tn*4+u][kk]; xv[u] = Xs[tm*4+u][kk]; }
      #pragma unroll
      for (int i = 0; i < 4; ++i)
        #pragma unroll
        for (int j = 0; j < 4; ++j) acc[i][j] += xv[i] * av[j];
    }
    __syncthreads();
  }
  #pragma unroll
  for (int i = 0; i < 4; ++i) {
    int m = bm + tm * 4 + i;
    if (m >= M) continue;
    #pragma unroll
    for (int j = 0; j < 4; ++j) {
      int n = bn + tn * 4 + j;
      float r = acc[i][j];
      if (b1) r += b1[n];
      if (b2) r += b2[n];
      Out[(size_t)m * ldo + n] = r;
    }
  }
}

__global__ void diag_k(const float* __restrict__ wh, const float* __restrict__ wht,
                       float* __restrict__ diag)
{
  int i = blockIdx.x * 256 + threadIdx.x;
  if (i < 2048) {
    int l = i >> 10, h = i & 1023;
    size_t idx = (size_t)l * 1048576 + (size_t)h * 1025;
    diag[i]        = wh[idx];
    diag[2048 + i] = wht[idx];
  }
}

__global__ __launch_bounds__(256) void phase1_l0_k(const float* __restrict__ XI0,
    float* __restrict__ tapeh, float* __restrict__ tapec, float* __restrict__ h0p1)
{
  int t = blockIdx.x;
  #pragma unroll
  for (int r = 0; r < 4; ++r) {
    int c = threadIdx.x + r * 256;
    float gi = XI0[t*4096 + c];
    float gg = XI0[t*4096 + 2048 + c];
    float go = XI0[t*4096 + 3072 + c];
    float cc = sigf(gi) * tanhf(gg);
    float hh = sigf(go) * tanhf(cc);
    tapeh[t*2048 + c] = hh;
    tapec[t*2048 + c] = cc;
    h0p1[t*1024 + c] = hh;
  }
}

__global__ __launch_bounds__(256) void phase1_l1_k(const float* __restrict__ G1,
    float* __restrict__ tapeh, float* __restrict__ tapec)
{
  int t = blockIdx.x;
  #pragma unroll
  for (int r = 0; r < 4; ++r) {
    int c = threadIdx.x + r * 256;
    float gi = G1[t*4096 + c];
    float gg = G1[t*4096 + 2048 + c];
    float go = G1[t*4096 + 3072 + c];
    float cc = sigf(gi) * tanhf(gg);
    float hh = sigf(go) * tanhf(cc);
    tapeh[t*2048 + 1024 + c] = hh;
    tapec[t*2048 + 1024 + c] = cc;
  }
}

// ---------------------------------------------------------------------------
// Counter barrier: 8 spread counters (1 cacheline apart). Arrival = one RMW
// at the coherence point; wait = 8 lanes polling 8 counters. Monotonic.
// ---------------------------------------------------------------------------
__device__ __forceinline__ void g_arrive(unsigned* __restrict__ bar) {
  asm volatile("s_waitcnt vmcnt(0)" ::: "memory");
  __syncthreads();
  if (threadIdx.x == 0)
    __hip_atomic_fetch_add(&bar[(blockIdx.x & 7) * 16], 1u,
                           __ATOMIC_RELAXED, __HIP_MEMORY_SCOPE_AGENT);
}
__device__ __forceinline__ void g_wait(unsigned* __restrict__ bar, unsigned ep) {
  if (threadIdx.x < 8) {
    const unsigned target = ep << 5;   // 32 WGs per counter
    for (;;) {
      unsigned v = __hip_atomic_load(&bar[threadIdx.x * 16],
                                     __ATOMIC_RELAXED, __HIP_MEMORY_SCOPE_AGENT);
      if (__all((int)(v >= target))) break;
      __builtin_amdgcn_s_sleep(1);
    }
  }
  __syncthreads();
  asm volatile("" ::: "memory");
}

__device__ __forceinline__ float red32(float p) {
  #pragma unroll
  for (int o = 16; o >= 1; o >>= 1) p += __shfl_xor(p, o, 64);
  return p;  // per-32-lane-half sum
}

__device__ __forceinline__ float red512(float p, float* sred) {
  const int tid = threadIdx.x;
  #pragma unroll
  for (int o = 32; o >= 1; o >>= 1) p += __shfl_xor(p, o, 64);
  if ((tid & 63) == 0) sred[tid >> 6] = p;
  __syncthreads();
  float r = sred[0] + sred[1] + sred[2] + sred[3] + sred[4] + sred[5] + sred[6] + sred[7];
  __syncthreads();
  return r;
}

__device__ __forceinline__ void red512x2(float& p0, float& p1, float* sred) {
  const int tid = threadIdx.x;
  #pragma unroll
  for (int o = 32; o >= 1; o >>= 1) {
    p0 += __shfl_xor(p0, o, 64);
    p1 += __shfl_xor(p1, o, 64);
  }
  if ((tid & 63) == 0) { sred[tid >> 6] = p0; sred[8 + (tid >> 6)] = p1; }
  __syncthreads();
  float a = 0.f, b = 0.f;
  #pragma unroll
  for (int i = 0; i < 8; ++i) { a += sred[i]; b += sred[8 + i]; }
  p0 = a; p1 = b;
  __syncthreads();
}

// ---------------------------------------------------------------------------
// Persistent cooperative scan: 256 WGs x 512 thr, 2 counter-barriers/step,
// compute hoisted into the arrive->wait windows.
// ---------------------------------------------------------------------------
__global__ __launch_bounds__(512, 2) void scan_fused(
    const float* __restrict__ wih1, const float* __restrict__ whh,
    const float* __restrict__ bih1, const float* __restrict__ bhh1,
    const float* __restrict__ diag, const float* __restrict__ av,
    const float* __restrict__ XI0, const float* __restrict__ XA,
    const float* __restrict__ tapehG, const float* __restrict__ tapecG,
    const float* __restrict__ P0g, const float* __restrict__ P1g,
    float* __restrict__ scoresG, float* __restrict__ prevh,
    float* __restrict__ h0cur, float* __restrict__ h1cur,
    float* __restrict__ outp, unsigned* __restrict__ bar)
{
  const int wg = blockIdx.x, tid = threadIdx.x;
  const int rid = tid >> 5, sub = tid & 31;
  const int row = ((rid & 12) << 8) + (wg << 2) + (rid & 3);
  const bool isScore = (wg < 58);
  const int lw = (wg < 29) ? 0 : 1;
  const int ii = (wg < 29) ? wg : wg - 29;
  const int h2 = tid * 2;

  __shared__ float tape[30 * 1024];
  __shared__ float hbuf[33 * 32];
  __shared__ float Pl0[30 * 17], Pl1[30 * 17];
  __shared__ float tcs[30 * 9];
  __shared__ float sc[64];
  __shared__ float a0[32], a1[32];
  __shared__ float gls[16], u1s[16], ncs[8], bsum[16], c0l[4];
  __shared__ float sred[16];

  // ---- one-time init ----
  float wih1r[32], whh0r[32], whh1r[32];
  {
    const float* p1 = wih1 + (size_t)row * 1024 + sub * 32;
    const float* p2 = whh  + (size_t)row * 1024 + sub * 32;
    const float* p3 = whh  + LSTRIDE + (size_t)row * 1024 + sub * 32;
    #pragma unroll
    for (int i = 0; i < 8; ++i) {
      float4 v1 = ((const float4*)p1)[i];
      wih1r[4*i+0]=v1.x; wih1r[4*i+1]=v1.y; wih1r[4*i+2]=v1.z; wih1r[4*i+3]=v1.w;
      float4 v2 = ((const float4*)p2)[i];
      whh0r[4*i+0]=v2.x; whh0r[4*i+1]=v2.y; whh0r[4*i+2]=v2.z; whh0r[4*i+3]=v2.w;
      float4 v3 = ((const float4*)p3)[i];
      whh1r[4*i+0]=v3.x; whh1r[4*i+1]=v3.y; whh1r[4*i+2]=v3.z; whh1r[4*i+3]=v3.w;
    }
  }
  if (sub == 0) bsum[rid] = bih1[row] + bhh1[row];
  for (int k = tid; k < 480; k += 512) {
    int s = k >> 4, r = k & 15;
    int rr = ((r & 12) << 8) + (wg << 2) + (r & 3);
    Pl0[s * 17 + r] = P0g[s * 4096 + rr];
    Pl1[s * 17 + r] = P1g[s * 4096 + rr];
  }
  for (int k = tid; k < 240; k += 512) {
    int s = k >> 3, c = k & 7;
    tcs[s * 9 + c] = tapecG[s * 2048 + ((c >> 2) << 10) + (wg << 2) + (c & 3)];
  }
  if (isScore) {
    for (int k = tid; k < 7680; k += 512) {
      int s = k >> 8, off = (k & 255) << 2;
      *(float4*)&tape[s * 1024 + off] =
          *(const float4*)&tapehG[s * 2048 + lw * 1024 + off];
    }
  }
  // per-thread attn constants (registers for the whole kernel)
  const float d0x = diag[h2],        d0y = diag[h2 + 1];
  const float t0x = diag[2048 + h2], t0y = diag[2048 + h2 + 1];
  const float v0x = av[h2],          v0y = av[h2 + 1];
  const float d1x = diag[1024 + h2], d1y = diag[1024 + h2 + 1];
  const float t1x = diag[3072 + h2], t1y = diag[3072 + h2 + 1];
  const float v1x = av[1024 + h2],   v1y = av[1024 + h2 + 1];
  const float dLx = lw ? d1x : d0x,  dLy = lw ? d1y : d0y;
  const float tLx = lw ? t1x : t0x,  tLy = lw ? t1y : t0y;
  const float vLx = lw ? v1x : v0x,  vLy = lw ? v1y : v0y;
  __syncthreads();

  unsigned ep = 0;

  // ---- bootstrap scores for t=30 (prev_h = 0) ----
  if (isScore) {
    for (int s = ii; s < 30; s += 29) {
      float2 tp = *(float2*)&tape[s * 1024 + h2];
      float2 xa = *(const float2*)&XA[(size_t)30 * 2048 + lw * 1024 + h2];
      float part = vLx * tanhf(dLx * tp.x + xa.x) + vLy * tanhf(dLy * tp.y + xa.y);
      float tot = red512(part, sred);
      if (tid == 0) cstore(&scoresG[lw * 30 + s], tot);
    }
  }
  g_arrive(bar);
  g_wait(bar, ++ep);

  for (int t = 30; t < 512; ++t) {
    const int tmod = t % 30;
    const int pslot = (tmod == 0) ? 29 : tmod - 1;
    const int pp = (t - 1) & 1;
    // ================= phase X =================
    if (tid < 60) sc[tid] = cload(&scoresG[(t & 1) * 64 + tid]);
    float xi = (sub == 0) ? XI0[(size_t)t * 4096 + row] : 0.f;
    if (t > 30) {
      float2 hv1 = cload2(&h1cur[pp * 1024 + h2]);          // h1(t-1)
      float2 th0 = cload2(&h0cur[pp * 1024 + h2]);          // h0(t-1)
      float2 ph0 = cload2(&prevh[pp * 2048 + h2]);
      float2 ph1 = cload2(&prevh[pp * 2048 + 1024 + h2]);
      float2 xa0 = *(const float2*)&XA[(size_t)t * 2048 + h2];
      float2 xa1 = *(const float2*)&XA[(size_t)t * 2048 + 1024 + h2];
      hbuf[(h2 & 31) * 33 + (h2 >> 5)]             = hv1.x;
      hbuf[((h2 + 1) & 31) * 33 + ((h2 + 1) >> 5)] = hv1.y;
      if (isScore) {
        float2 tv = lw ? hv1 : th0;
        *(float2*)&tape[pslot * 1024 + h2] = tv;
      }
      float np0 = v0x * tanhf(d0x * th0.x + xa0.x + t0x * ph0.x)
                + v0y * tanhf(d0y * th0.y + xa0.y + t0y * ph0.y);
      float np1 = v1x * tanhf(d1x * hv1.x + xa1.x + t1x * ph1.x)
                + v1y * tanhf(d1y * hv1.y + xa1.y + t1y * ph1.y);
      red512x2(np0, np1, sred);   // internal syncthreads cover hbuf/tape writes
      if (tid == 0) { sc[pslot] = np0; sc[30 + pslot] = np1; }
      float pc = 0.f;
      #pragma unroll
      for (int i = 0; i < 32; ++i) pc += whh1r[i] * hbuf[i * 33 + sub];
      pc = red32(pc);
      if (sub == 0) Pl1[pslot * 17 + rid] = pc;
    }
    __syncthreads();
    // softmax over tape dim, both layers (wave 0)
    if (tid < 64) {
      int l = tid >> 5, s2 = tid & 31;
      float v = (s2 < 30) ? sc[l * 30 + s2] : -1e30f;
      float m = v;
      #pragma unroll
      for (int o = 16; o >= 1; o >>= 1) m = fmaxf(m, __shfl_xor(m, o, 64));
      float e = (s2 < 30) ? expf(v - m) : 0.f;
      float sm = e;
      #pragma unroll
      for (int o = 16; o >= 1; o >>= 1) sm += __shfl_xor(sm, o, 64);
      (l ? a1 : a0)[s2] = e / sm;
    }
    __syncthreads();
    // gates0 / u1 / c-tape sums
    {
      float p = (sub < 30) ? a0[sub] * Pl0[sub * 17 + rid] : 0.f;
      p = red32(p);
      if (sub == 0) gls[rid] = p + xi;
      float pu = (sub < 30) ? a1[sub] * Pl1[sub * 17 + rid] : 0.f;
      pu = red32(pu);
      if (sub == 0) u1s[rid] = pu;
      float pn = 0.f;
      if (rid < 8 && sub < 30)
        pn = (rid < 4 ? a0[sub] : a1[sub]) * tcs[sub * 9 + (rid & 4) + (rid & 3)];
      pn = red32(pn);
      if (rid < 8 && sub == 0) ncs[rid] = pn;
    }
    __syncthreads();
    if (tid < 4) {
      float gi = gls[tid], gf = gls[4 + tid], gg = gls[8 + tid], go = gls[12 + tid];
      float c0 = sigf(gf) * ncs[tid] + sigf(gi) * tanhf(gg);
      float h0 = sigf(go) * tanhf(c0);
      c0l[tid] = c0;
      cstore(&h0cur[(t & 1) * 1024 + (wg << 2) + tid], h0);
    }
    g_arrive(bar);
    // --- hidden in wait window: t+1 old-slot scores + prevh publication ---
    if (isScore && t < 511) {
      int ss = tmod + 1 + ii; if (ss >= 30) ss -= 30;
      const float* aL = lw ? a1 : a0;
      float accx = 0.f, accy = 0.f;
      #pragma unroll
      for (int s = 0; s < 30; ++s) {
        float as = aL[s];
        float2 tv = *(float2*)&tape[s * 1024 + h2];
        accx += as * tv.x;
        accy += as * tv.y;
      }
      if (ii == 0) cstore2(&prevh[(t & 1) * 2048 + lw * 1024 + h2],
                           make_float2(accx, accy));
      float2 ts = *(float2*)&tape[ss * 1024 + h2];
      float2 xa = *(const float2*)&XA[(size_t)(t + 1) * 2048 + lw * 1024 + h2];
      float part = vLx * tanhf(dLx * ts.x + xa.x + tLx * accx)
                 + vLy * tanhf(dLy * ts.y + xa.y + tLy * accy);
      float tot = red512(part, sred);
      if (tid == 0) cstore(&scoresG[((t + 1) & 1) * 64 + lw * 30 + ss], tot);
    }
    g_wait(bar, ++ep);
    // ================= phase Y =================
    {
      float2 h0v = cload2(&h0cur[(t & 1) * 1024 + h2]);
      hbuf[(h2 & 31) * 33 + (h2 >> 5)]             = h0v.x;
      hbuf[((h2 + 1) & 31) * 33 + ((h2 + 1) >> 5)] = h0v.y;
    }
    __syncthreads();
    {
      float m1 = 0.f;
      #pragma unroll
      for (int i = 0; i < 32; ++i) m1 += wih1r[i] * hbuf[i * 33 + sub];
      m1 = red32(m1);
      if (sub == 0) gls[rid] = m1 + u1s[rid] + bsum[rid];
    }
    __syncthreads();
    if (tid < 4) {
      int j = (wg << 2) + tid;
      float gi = gls[tid], gf = gls[4 + tid], gg = gls[8 + tid], go = gls[12 + tid];
      float c1 = sigf(gf) * ncs[4 + tid] + sigf(gi) * tanhf(gg);
      float h1 = sigf(go) * tanhf(c1);
      outp[(size_t)(t - TAPE_N) * 1024 + j] = h1;
      cstore(&h1cur[(t & 1) * 1024 + j], h1);
      tcs[tmod * 9 + tid] = c0l[tid];
      tcs[tmod * 9 + 4 + tid] = c1;
    }
    if (t == 511) break;
    g_arrive(bar);
    // --- hidden in wait window: P0 column update (w_hh0 @ h0(t)) ---
    {
      float pc0 = 0.f;
      #pragma unroll
      for (int i = 0; i < 32; ++i) pc0 += whh0r[i] * hbuf[i * 33 + sub];
      pc0 = red32(pc0);
      if (sub == 0) Pl0[tmod * 17 + rid] = pc0;
    }
    g_wait(bar, ++ep);
  }
}

// ---------------------------------------------------------------------------
extern "C" void kernel_launch(void* const* d_in, const int* in_sizes, int n_in,
                              void* d_out, int out_size, void* d_ws, size_t ws_size,
                              hipStream_t stream) {
  (void)in_sizes; (void)n_in; (void)out_size; (void)ws_size;
  const float* xs    = (const float*)d_in[0];
  const float* w_ih  = (const float*)d_in[1];
  const float* w_hh  = (const float*)d_in[2];
  const float* b_ih  = (const float*)d_in[3];
  const float* b_hh  = (const float*)d_in[4];
  const float* a_wh  = (const float*)d_in[5];
  const float* a_wx  = (const float*)d_in[6];
  const float* a_wht = (const float*)d_in[7];
  const float* a_v   = (const float*)d_in[8];
  float* outp = (float*)d_out;

  float* ws     = (float*)d_ws;
  float* XI0    = ws;                      // 512*4096
  float* XA     = XI0    + 512 * 4096;     // 512*2048
  float* tapehG = XA     + 512 * 2048;     // 30*2048
  float* tapecG = tapehG + 30 * 2048;      // 30*2048
  float* P0g    = tapecG + 30 * 2048;      // 30*4096
  float* P1g    = P0g    + 30 * 4096;      // 30*4096
  float* diag   = P1g    + 30 * 4096;      // 4096
  float* scor   = diag   + 4096;           // 2*64
  float* prevh  = scor   + 128;            // 2*2048
  float* h0cur  = prevh  + 4096;           // 2*1024
  float* h1cur  = h0cur  + 2048;           // 2*1024
  float* h0p1   = h1cur  + 2048;           // 30*1024
  float* G1b    = h0p1   + 30 * 1024;      // 30*4096
  unsigned* bar = (unsigned*)(G1b + 30 * 4096);  // 8 counters, 16 u32 apart

  hipMemsetAsync(outp + (size_t)482 * 1024, 0, 30 * 1024 * sizeof(float), stream);
  hipMemsetAsync(bar, 0, 1024, stream);

  diag_k<<<8, 256, 0, stream>>>(a_wh, a_wht, diag);

  gemm_nt<<<dim3(64, 8), 256, 0, stream>>>(w_ih, xs, XI0, b_ih, b_hh, 512, 1024, 4096);
  gemm_nt<<<dim3(16, 8), 256, 0, stream>>>(a_wx, xs, XA, nullptr, nullptr, 512, 1024, 2048);
  gemm_nt<<<dim3(16, 8), 256, 0, stream>>>(a_wx + LSTRIDE / 4, xs, XA + 1024, nullptr, nullptr, 512, 1024, 2048);

  phase1_l0_k<<<30, 256, 0, stream>>>(XI0, tapehG, tapecG, h0p1);
  gemm_nt<<<dim3(64, 1), 256, 0, stream>>>(w_ih + LSTRIDE, h0p1, G1b, b_ih + 4096, b_hh + 4096, 30, 1024, 4096);
  phase1_l1_k<<<30, 256, 0, stream>>>(G1b, tapehG, tapecG);

  gemm_nt<<<dim3(64, 1), 256, 0, stream>>>(w_hh, tapehG, P0g, nullptr, nullptr, 30, 2048, 4096);
  gemm_nt<<<dim3(64, 1), 256, 0, stream>>>(w_hh + LSTRIDE, tapehG + 1024, P1g, nullptr, nullptr, 30, 2048, 4096);

  const float* wih1p = w_ih + LSTRIDE;
  const float* whhp  = w_hh;
  const float* bih1p = b_ih + 4096;
  const float* bhh1p = b_hh + 4096;
  void* kargs[] = {
    (void*)&wih1p, (void*)&whhp, (void*)&bih1p, (void*)&bhh1p,
    (void*)&diag,  (void*)&a_v,  (void*)&XI0,   (void*)&XA,
    (void*)&tapehG, (void*)&tapecG, (void*)&P0g, (void*)&P1g,
    (void*)&scor,  (void*)&prevh, (void*)&h0cur, (void*)&h1cur,
    (void*)&outp,  (void*)&bar
  };
  hipLaunchCooperativeKernel((void*)scan_fused, dim3(256), dim3(512), kargs, 0, stream);
}

// Round 5
// 4456.420 us; speedup vs baseline: 3.3809x; 1.1297x over previous
//
#include <hip/hip_runtime.h>
#include <math.h>

#define LSTRIDE 4194304   // 4096*1024

__device__ __forceinline__ float sigf(float x) { return 1.0f / (1.0f + expf(-x)); }

// Coherent (L2-bypassing) access for ALL cross-WG data => no fences needed.
__device__ __forceinline__ float cload(const float* p) {
  return __hip_atomic_load(p, __ATOMIC_RELAXED, __HIP_MEMORY_SCOPE_AGENT);
}
__device__ __forceinline__ void cstore(float* p, float v) {
  __hip_atomic_store(p, v, __ATOMIC_RELAXED, __HIP_MEMORY_SCOPE_AGENT);
}
__device__ __forceinline__ float2 cload2(const float* p) {
  unsigned long long v = __hip_atomic_load((const unsigned long long*)p,
                                           __ATOMIC_RELAXED, __HIP_MEMORY_SCOPE_AGENT);
  float2 r;
  r.x = __uint_as_float((unsigned)v);
  r.y = __uint_as_float((unsigned)(v >> 32));
  return r;
}
__device__ __forceinline__ void cstore2(float* p, float2 v) {
  unsigned long long u = ((unsigned long long)__float_as_uint(v.y) << 32) |
                         (unsigned long long)__float_as_uint(v.x);
  __hip_atomic_store((unsigned long long*)p, u, __ATOMIC_RELAXED, __HIP_MEMORY_SCOPE_AGENT);
}

// ---------------------------------------------------------------------------
// Generic GEMM: Out[m*ldo + n] = sum_k A[n*1024 + k] * X[m*ldx + k] (+ b1 + b2)
// ---------------------------------------------------------------------------
__global__ __launch_bounds__(256) void gemm_nt(
    const float* __restrict__ A, const float* __restrict__ X, float* __restrict__ Out,
    const float* __restrict__ b1, const float* __restrict__ b2,
    int M, int ldx, int ldo)
{
  __shared__ float As[64][65];
  __shared__ float Xs[64][65];
  const int tid = threadIdx.x;
  const int tn = tid & 15, tm = tid >> 4;
  const int bn = blockIdx.x * 64, bm = blockIdx.y * 64;
  float acc[4][4];
  #pragma unroll
  for (int i = 0; i < 4; ++i)
    #pragma unroll
    for (int j = 0; j < 4; ++j) acc[i][j] = 0.f;

  for (int k0 = 0; k0 < 1024; k0 += 64) {
    #pragma unroll
    for (int r = 0; r < 4; ++r) {
      int linear = r * 1024 + tid * 4;
      int nn = linear >> 6, kk = linear & 63;
      float4 av = *(const float4*)(A + (size_t)(bn + nn) * 1024 + k0 + kk);
      As[nn][kk+0] = av.x; As[nn][kk+1] = av.y; As[nn][kk+2] = av.z; As[nn][kk+3] = av.w;
      float4 xv = make_float4(0.f, 0.f, 0.f, 0.f);
      if (bm + nn < M) xv = *(const float4*)(X + (size_t)(bm + nn) * ldx + k0 + kk);
      Xs[nn][kk+0] = xv.x; Xs[nn][kk+1] = xv.y; Xs[nn][kk+2] = xv.z; Xs[nn][kk+3] = xv.w;
    }
    __syncthreads();
    #pragma unroll 16
    for (int kk = 0; kk < 64; ++kk) {
      float av[4], xv[4];
      #pragma unroll
      for (int u = 0; u < 4; ++u) { av[u] = As[tn*4+u][kk]; xv[u] = Xs[tm*4+u][kk]; }
      #pragma unroll
      for (int i = 0; i < 4; ++i)
        #pragma unroll
        for (int j = 0; j < 4; ++j) acc[i][j] += xv[i] * av[j];
    }
    __syncthreads();
  }
  #pragma unroll
  for (int i = 0; i < 4; ++i) {
    int m = bm + tm * 4 + i;
    if (m >= M) continue;
    #pragma unroll
    for (int j = 0; j < 4; ++j) {
      int n = bn + tn * 4 + j;
      float r = acc[i][j];
      if (b1) r += b1[n];
      if (b2) r += b2[n];
      Out[(size_t)m * ldo + n] = r;
    }
  }
}

__global__ void diag_k(const float* __restrict__ wh, const float* __restrict__ wht,
                       float* __restrict__ diag)
{
  int i = blockIdx.x * 256 + threadIdx.x;
  if (i < 2048) {
    int l = i >> 10, h = i & 1023;
    size_t idx = (size_t)l * 1048576 + (size_t)h * 1025;
    diag[i]        = wh[idx];
    diag[2048 + i] = wht[idx];
  }
}

__global__ __launch_bounds__(256) void phase1_l0_k(const float* __restrict__ XI0,
    float* __restrict__ tapeh, float* __restrict__ tapec, float* __restrict__ h0p1)
{
  int t = blockIdx.x;
  #pragma unroll
  for (int r = 0; r < 4; ++r) {
    int c = threadIdx.x + r * 256;
    float gi = XI0[t*4096 + c];
    float gg = XI0[t*4096 + 2048 + c];
    float go = XI0[t*4096 + 3072 + c];
    float cc = sigf(gi) * tanhf(gg);
    float hh = sigf(go) * tanhf(cc);
    tapeh[t*2048 + c] = hh;
    tapec[t*2048 + c] = cc;
    h0p1[t*1024 + c] = hh;
  }
}

__global__ __launch_bounds__(256) void phase1_l1_k(const float* __restrict__ G1,
    float* __restrict__ tapeh, float* __restrict__ tapec)
{
  int t = blockIdx.x;
  #pragma unroll
  for (int r = 0; r < 4; ++r) {
    int c = threadIdx.x + r * 256;
    float gi = G1[t*4096 + c];
    float gg = G1[t*4096 + 2048 + c];
    float go = G1[t*4096 + 3072 + c];
    float cc = sigf(gi) * tanhf(gg);
    float hh = sigf(go) * tanhf(cc);
    tapeh[t*2048 + 1024 + c] = hh;
    tapec[t*2048 + 1024 + c] = cc;
  }
}

__device__ __forceinline__ float red16(float p) {
  #pragma unroll
  for (int o = 8; o >= 1; o >>= 1) p += __shfl_xor(p, o, 16);
  return p;  // per-16-lane-group sum
}

// ---------------------------------------------------------------------------
// Pipelined persistent scan. LW=0: 128 WGs run the layer-0 recurrence with
// barrier bar0 (counters 0..3). LW=1: 128 WGs run layer-1, one step behind,
// on bar1 (counters 4..7), consuming h0 via bar0's count. One barrier/step.
// Arrival at end of epoch e = count 32*(e-28) per counter (bootstrap = #1).
// ---------------------------------------------------------------------------
template <int LW>
__device__ __forceinline__ void run_group(
    const int gw,
    const float* __restrict__ wih, const float* __restrict__ whh,
    const float* __restrict__ bih, const float* __restrict__ bhh,
    const float* __restrict__ diag, const float* __restrict__ av,
    const float* __restrict__ XI0, const float* __restrict__ XA,
    const float* __restrict__ tapehG, const float* __restrict__ tapecG,
    const float* __restrict__ Pg,
    float* __restrict__ scoresG, float* __restrict__ prevh,
    float* __restrict__ h0cur, float* __restrict__ h1cur,
    float* __restrict__ outp, unsigned* __restrict__ bar,
    float* tape, float* hA, float* hB, float* Pl, float* tc,
    float* sc, float* aw, float* gls, float* ihs, float* ncs,
    float* bsum, float* sred)
{
  const int tid = threadIdx.x;
  const int rid = tid >> 4, sub = tid & 15;       // 32 row-slots x 16 lanes
  const int cell = (gw << 3) + (rid & 7);
  const int row = ((rid >> 3) << 10) + cell;      // gate*1024 + cell
  const bool isScore = (gw < 29);
  const int h2 = tid * 2;

  // ---- one-time init: weights -> VGPRs, P/tape/tc -> LDS ----
  float wA[64];
  float wB[LW ? 64 : 1];
  {
    const float* pa = whh + (size_t)LW * LSTRIDE + (size_t)row * 1024 + sub * 64;
    #pragma unroll
    for (int i = 0; i < 16; ++i) {
      float4 v = ((const float4*)pa)[i];
      wA[4*i] = v.x; wA[4*i+1] = v.y; wA[4*i+2] = v.z; wA[4*i+3] = v.w;
    }
    if (LW) {
      const float* pb = wih + LSTRIDE + (size_t)row * 1024 + sub * 64;
      #pragma unroll
      for (int i = 0; i < 16; ++i) {
        float4 v = ((const float4*)pb)[i];
        wB[4*i] = v.x; wB[4*i+1] = v.y; wB[4*i+2] = v.z; wB[4*i+3] = v.w;
      }
    }
  }
  if (LW && sub == 0) bsum[rid] = bih[4096 + row] + bhh[4096 + row];
  for (int k = tid; k < 960; k += 512) {
    int s = k >> 5, r = k & 31;
    int rr = ((r >> 3) << 10) + (gw << 3) + (r & 7);
    Pl[s * 34 + r] = Pg[s * 4096 + rr];
  }
  for (int k = tid; k < 240; k += 512) {
    int s = k >> 3, c = k & 7;
    tc[s * 9 + c] = tapecG[s * 2048 + LW * 1024 + (gw << 3) + c];
  }
  if (isScore) {
    for (int k = tid; k < 7680; k += 512) {
      int s = k >> 8, off = (k & 255) << 2;
      *(float4*)&tape[s * 1024 + off] =
          *(const float4*)&tapehG[s * 2048 + LW * 1024 + off];
    }
  }
  const float ddx = diag[LW*1024 + h2],        ddy = diag[LW*1024 + h2 + 1];
  const float ttx = diag[2048 + LW*1024 + h2], tty = diag[2048 + LW*1024 + h2 + 1];
  const float vvx = av[LW*1024 + h2],          vvy = av[LW*1024 + h2 + 1];
  __syncthreads();

  // ---- bootstrap: scores(t=30) for all 30 slots (prev_h = 0) ----
  if (isScore) {
    for (int s = gw; s < 30; s += 29) {
      float2 xa = *(const float2*)&XA[(size_t)30 * 2048 + LW * 1024 + h2];
      float part = vvx * tanhf(ddx * tape[s*1024 + h2] + xa.x)
                 + vvy * tanhf(ddy * tape[s*1024 + h2 + 1] + xa.y);
      #pragma unroll
      for (int o = 32; o >= 1; o >>= 1) part += __shfl_xor(part, o, 64);
      if ((tid & 63) == 0) sred[tid >> 6] = part;
      __syncthreads();
      if (tid == 0) {
        float tot = 0.f;
        #pragma unroll
        for (int i = 0; i < 8; ++i) tot += sred[i];
        cstore(&scoresG[LW * 32 + s], tot);
      }
      __syncthreads();
    }
  }
  asm volatile("s_waitcnt vmcnt(0)" ::: "memory");
  __syncthreads();
  if (tid == 0)
    __hip_atomic_fetch_add(&bar[(LW * 4 + (gw >> 5)) * 32], 1u,
                           __ATOMIC_RELAXED, __HIP_MEMORY_SCOPE_AGENT);

  for (int t = 30; t < 512; ++t) {
    // ---- wait (8 lanes; lanes 4..7 = cross-group dependency) ----
    if (tid < 8) {
      unsigned tgt;
      if (LW == 0)
        tgt = (tid < 4) ? 32u * (unsigned)(t - 29)
                        : (t >= 33 ? 32u * (unsigned)(t - 32) : 0u);  // backpressure
      else
        tgt = (tid < 4) ? 32u * (unsigned)(t - 28)    // h0(t) ready
                        : 32u * (unsigned)(t - 29);   // own prior epoch
      if (tgt) {
        for (;;) {
          unsigned v = __hip_atomic_load(&bar[tid * 32],
                                         __ATOMIC_RELAXED, __HIP_MEMORY_SCOPE_AGENT);
          if (__all((int)(v >= tgt))) break;
          __builtin_amdgcn_s_sleep(1);
        }
      }
    }
    __syncthreads();
    const int tmod = t % 30;
    const int pslot = (tmod == 0) ? 29 : tmod - 1;

    // ---- epoch-start loads (all independent, issued together) ----
    if (tid < 30) sc[tid] = cload(&scoresG[(t & 1) * 64 + LW * 32 + tid]);
    float2 hva, hvb = make_float2(0.f, 0.f), ph = make_float2(0.f, 0.f),
           xan = make_float2(0.f, 0.f);
    if (LW == 0) {
      hva = cload2(&h0cur[(size_t)((t - 1) & 3) * 1024 + h2]);   // h0(t-1)
    } else {
      hva = cload2(&h0cur[(size_t)(t & 3) * 1024 + h2]);         // h0(t)
      hvb = cload2(&h1cur[((t - 1) & 1) * 1024 + h2]);           // h1(t-1)
    }
    if (t > 30) {
      ph  = cload2(&prevh[((t - 1) & 1) * 2048 + LW * 1024 + h2]);
      xan = *(const float2*)&XA[(size_t)t * 2048 + LW * 1024 + h2];
    }
    float xi = 0.f;
    if (LW == 0 && sub == 0) xi = XI0[(size_t)t * 4096 + row];
    {
      int o = (h2 >> 6) * 66 + (h2 & 63);
      hA[o] = hva.x; hA[o + 1] = hva.y;
      if (LW) { hB[o] = hvb.x; hB[o + 1] = hvb.y; }
    }
    __syncthreads();

    // ---- new-slot score partial + P-col matvec + tape refresh ----
    if (t > 30) {
      float2 hn = LW ? hvb : hva;                 // own-layer h(t-1)
      float np = vvx * tanhf(ddx * hn.x + xan.x + ttx * ph.x)
               + vvy * tanhf(ddy * hn.y + xan.y + tty * ph.y);
      #pragma unroll
      for (int o = 32; o >= 1; o >>= 1) np += __shfl_xor(np, o, 64);
      if ((tid & 63) == 0) sred[tid >> 6] = np;
      const float* hbufP = LW ? hB : hA;
      float pc = 0.f;
      #pragma unroll
      for (int i = 0; i < 64; ++i) pc += wA[i] * hbufP[sub * 66 + i];
      pc = red16(pc);
      if (sub == 0) Pl[pslot * 34 + rid] = pc;
      if (isScore) {
        tape[pslot * 1024 + h2]     = hn.x;
        tape[pslot * 1024 + h2 + 1] = hn.y;
      }
    }
    if (LW) {  // w_ih1 @ h0(t), every epoch
      float ih = 0.f;
      #pragma unroll
      for (int i = 0; i < 64; ++i) ih += wB[i] * hA[sub * 66 + i];
      ih = red16(ih);
      if (sub == 0) ihs[rid] = ih + bsum[rid];
    }
    __syncthreads();

    // ---- softmax (wave 0, new-slot score folded in) ----
    if (tid < 32) {
      float npv = 0.f;
      if (t > 30) {
        float x = (tid < 8) ? sred[tid] : 0.f;
        #pragma unroll
        for (int o = 4; o >= 1; o >>= 1) x += __shfl_xor(x, o, 8);
        npv = __shfl(x, 0, 32);
      }
      float v = (tid < 30) ? sc[tid] : -1e30f;
      if (t > 30 && tid == pslot) v = npv;
      float m = v;
      #pragma unroll
      for (int o = 16; o >= 1; o >>= 1) m = fmaxf(m, __shfl_xor(m, o, 32));
      float e = (tid < 30) ? expf(v - m) : 0.f;
      float sm = e;
      #pragma unroll
      for (int o = 16; o >= 1; o >>= 1) sm += __shfl_xor(sm, o, 32);
      aw[tid] = e / sm;
    }
    __syncthreads();

    // ---- gates (alpha-weighted P) + c-tape sums ----
    {
      float p = aw[sub] * Pl[sub * 34 + rid];
      if (sub < 14) p += aw[sub + 16] * Pl[(sub + 16) * 34 + rid];
      p = red16(p);
      if (sub == 0) gls[rid] = p + (LW ? ihs[rid] : xi);
      if (rid < 8) {
        float pn = aw[sub] * tc[sub * 9 + rid];
        if (sub < 14) pn += aw[sub + 16] * tc[(sub + 16) * 9 + rid];
        pn = red16(pn);
        if (sub == 0) ncs[rid] = pn;
      }
    }
    __syncthreads();

    // ---- LSTM cell + publish ----
    if (tid < 8) {
      float gi = gls[tid], gf = gls[8 + tid], gg = gls[16 + tid], go = gls[24 + tid];
      float cv = sigf(gf) * ncs[tid] + sigf(gi) * tanhf(gg);
      float hv = sigf(go) * tanhf(cv);
      if (LW == 0) {
        cstore(&h0cur[(size_t)(t & 3) * 1024 + (gw << 3) + tid], hv);
      } else {
        outp[(size_t)(t - 30) * 1024 + (gw << 3) + tid] = hv;
        cstore(&h1cur[(t & 1) * 1024 + (gw << 3) + tid], hv);
      }
      tc[tmod * 9 + tid] = cv;
    }

    // ---- score WGs: old-slot scores for t+1 + prevh(t) ----
    if (isScore && t < 511) {
      int ss = tmod + 1 + gw; if (ss >= 30) ss -= 30;
      float ax = 0.f, ay = 0.f;
      #pragma unroll
      for (int s = 0; s < 30; ++s) {
        float as = aw[s];
        ax += as * tape[s * 1024 + h2];
        ay += as * tape[s * 1024 + h2 + 1];
      }
      if (gw == 0) cstore2(&prevh[(t & 1) * 2048 + LW * 1024 + h2],
                           make_float2(ax, ay));
      float2 xa2 = *(const float2*)&XA[(size_t)(t + 1) * 2048 + LW * 1024 + h2];
      float part = vvx * tanhf(ddx * tape[ss * 1024 + h2] + xa2.x + ttx * ax)
                 + vvy * tanhf(ddy * tape[ss * 1024 + h2 + 1] + xa2.y + tty * ay);
      #pragma unroll
      for (int o = 32; o >= 1; o >>= 1) part += __shfl_xor(part, o, 64);
      if ((tid & 63) == 0) sred[tid >> 6] = part;
      __syncthreads();
      if (tid == 0) {
        float tot = 0.f;
        #pragma unroll
        for (int i = 0; i < 8; ++i) tot += sred[i];
        cstore(&scoresG[((t + 1) & 1) * 64 + LW * 32 + ss], tot);
      }
    }

    // ---- arrive ----
    asm volatile("s_waitcnt vmcnt(0)" ::: "memory");
    __syncthreads();
    if (tid == 0)
      __hip_atomic_fetch_add(&bar[(LW * 4 + (gw >> 5)) * 32], 1u,
                             __ATOMIC_RELAXED, __HIP_MEMORY_SCOPE_AGENT);
  }
}

__global__ __launch_bounds__(512, 2) void scan_fused(
    const float* __restrict__ wih, const float* __restrict__ whh,
    const float* __restrict__ bih, const float* __restrict__ bhh,
    const float* __restrict__ diag, const float* __restrict__ av,
    const float* __restrict__ XI0, const float* __restrict__ XA,
    const float* __restrict__ tapehG, const float* __restrict__ tapecG,
    const float* __restrict__ P0g, const float* __restrict__ P1g,
    float* __restrict__ scoresG, float* __restrict__ prevh,
    float* __restrict__ h0cur, float* __restrict__ h1cur,
    float* __restrict__ outp, unsigned* __restrict__ bar)
{
  __shared__ float tape[30 * 1024];
  __shared__ float hA[16 * 66], hB[16 * 66];
  __shared__ float Pl[30 * 34];
  __shared__ float tc[30 * 9];
  __shared__ float sc[32], aw[32], gls[32], ihs[32], ncs[8], bsum[32], sred[8];
  if (blockIdx.x < 128)
    run_group<0>(blockIdx.x, wih, whh, bih, bhh, diag, av, XI0, XA, tapehG, tapecG,
                 P0g, scoresG, prevh, h0cur, h1cur, outp, bar,
                 tape, hA, hB, Pl, tc, sc, aw, gls, ihs, ncs, bsum, sred);
  else
    run_group<1>(blockIdx.x - 128, wih, whh, bih, bhh, diag, av, XI0, XA, tapehG, tapecG,
                 P1g, scoresG, prevh, h0cur, h1cur, outp, bar,
                 tape, hA, hB, Pl, tc, sc, aw, gls, ihs, ncs, bsum, sred);
}

// ---------------------------------------------------------------------------
extern "C" void kernel_launch(void* const* d_in, const int* in_sizes, int n_in,
                              void* d_out, int out_size, void* d_ws, size_t ws_size,
                              hipStream_t stream) {
  (void)in_sizes; (void)n_in; (void)out_size; (void)ws_size;
  const float* xs    = (const float*)d_in[0];
  const float* w_ih  = (const float*)d_in[1];
  const float* w_hh  = (const float*)d_in[2];
  const float* b_ih  = (const float*)d_in[3];
  const float* b_hh  = (const float*)d_in[4];
  const float* a_wh  = (const float*)d_in[5];
  const float* a_wx  = (const float*)d_in[6];
  const float* a_wht = (const float*)d_in[7];
  const float* a_v   = (const float*)d_in[8];
  float* outp = (float*)d_out;

  float* ws     = (float*)d_ws;
  float* XI0    = ws;                      // 512*4096
  float* XA     = XI0    + 512 * 4096;     // 512*2048
  float* tapehG = XA     + 512 * 2048;     // 30*2048
  float* tapecG = tapehG + 30 * 2048;      // 30*2048
  float* P0g    = tapecG + 30 * 2048;      // 30*4096
  float* P1g    = P0g    + 30 * 4096;      // 30*4096
  float* diag   = P1g    + 30 * 4096;      // 4096
  float* scor   = diag   + 4096;           // 2*64
  float* prevh  = scor   + 128;            // 2*2048
  float* h0cur  = prevh  + 4096;           // 4*1024 (depth-4)
  float* h1cur  = h0cur  + 4096;           // 2*1024
  float* h0p1   = h1cur  + 2048;           // 30*1024
  float* G1b    = h0p1   + 30 * 1024;      // 30*4096
  unsigned* bar = (unsigned*)(G1b + 30 * 4096);  // 8 counters, 32 u32 apart

  hipMemsetAsync(outp + (size_t)482 * 1024, 0, 30 * 1024 * sizeof(float), stream);
  hipMemsetAsync(bar, 0, 1024, stream);

  diag_k<<<8, 256, 0, stream>>>(a_wh, a_wht, diag);

  gemm_nt<<<dim3(64, 8), 256, 0, stream>>>(w_ih, xs, XI0, b_ih, b_hh, 512, 1024, 4096);
  gemm_nt<<<dim3(16, 8), 256, 0, stream>>>(a_wx, xs, XA, nullptr, nullptr, 512, 1024, 2048);
  gemm_nt<<<dim3(16, 8), 256, 0, stream>>>(a_wx + LSTRIDE / 4, xs, XA + 1024, nullptr, nullptr, 512, 1024, 2048);

  phase1_l0_k<<<30, 256, 0, stream>>>(XI0, tapehG, tapecG, h0p1);
  gemm_nt<<<dim3(64, 1), 256, 0, stream>>>(w_ih + LSTRIDE, h0p1, G1b, b_ih + 4096, b_hh + 4096, 30, 1024, 4096);
  phase1_l1_k<<<30, 256, 0, stream>>>(G1b, tapehG, tapecG);

  gemm_nt<<<dim3(64, 1), 256, 0, stream>>>(w_hh, tapehG, P0g, nullptr, nullptr, 30, 2048, 4096);
  gemm_nt<<<dim3(64, 1), 256, 0, stream>>>(w_hh + LSTRIDE, tapehG + 1024, P1g, nullptr, nullptr, 30, 2048, 4096);

  const float* wihp = w_ih;
  const float* whhp = w_hh;
  const float* bihp = b_ih;
  const float* bhhp = b_hh;
  void* kargs[] = {
    (void*)&wihp, (void*)&whhp, (void*)&bihp, (void*)&bhhp,
    (void*)&diag, (void*)&a_v,  (void*)&XI0,  (void*)&XA,
    (void*)&tapehG, (void*)&tapecG, (void*)&P0g, (void*)&P1g,
    (void*)&scor, (void*)&prevh, (void*)&h0cur, (void*)&h1cur,
    (void*)&outp, (void*)&bar
  };
  hipLaunchCooperativeKernel((void*)scan_fused, dim3(256), dim3(512), kargs, 0, stream);
}

// Round 6
// 3820.585 us; speedup vs baseline: 3.9436x; 1.1664x over previous
//
#include <hip/hip_runtime.h>
#include <math.h>

#define LSTRIDE 4194304   // 4096*1024

__device__ __forceinline__ float sigf(float x) { return 1.0f / (1.0f + expf(-x)); }

// Coherent (L2-bypassing) access for ALL cross-WG data => no fences needed.
__device__ __forceinline__ float cload(const float* p) {
  return __hip_atomic_load(p, __ATOMIC_RELAXED, __HIP_MEMORY_SCOPE_AGENT);
}
__device__ __forceinline__ void cstore(float* p, float v) {
  __hip_atomic_store(p, v, __ATOMIC_RELAXED, __HIP_MEMORY_SCOPE_AGENT);
}
__device__ __forceinline__ float2 cload2(const float* p) {
  unsigned long long v = __hip_atomic_load((const unsigned long long*)p,
                                           __ATOMIC_RELAXED, __HIP_MEMORY_SCOPE_AGENT);
  float2 r;
  r.x = __uint_as_float((unsigned)v);
  r.y = __uint_as_float((unsigned)(v >> 32));
  return r;
}
__device__ __forceinline__ void cstore2(float* p, float2 v) {
  unsigned long long u = ((unsigned long long)__float_as_uint(v.y) << 32) |
                         (unsigned long long)__float_as_uint(v.x);
  __hip_atomic_store((unsigned long long*)p, u, __ATOMIC_RELAXED, __HIP_MEMORY_SCOPE_AGENT);
}

// ---------------------------------------------------------------------------
// Generic GEMM: Out[m*ldo + n] = sum_k A[n*1024 + k] * X[m*ldx + k] (+ b1 + b2)
// ---------------------------------------------------------------------------
__global__ __launch_bounds__(256) void gemm_nt(
    const float* __restrict__ A, const float* __restrict__ X, float* __restrict__ Out,
    const float* __restrict__ b1, const float* __restrict__ b2,
    int M, int ldx, int ldo)
{
  __shared__ float As[64][65];
  __shared__ float Xs[64][65];
  const int tid = threadIdx.x;
  const int tn = tid & 15, tm = tid >> 4;
  const int bn = blockIdx.x * 64, bm = blockIdx.y * 64;
  float acc[4][4];
  #pragma unroll
  for (int i = 0; i < 4; ++i)
    #pragma unroll
    for (int j = 0; j < 4; ++j) acc[i][j] = 0.f;

  for (int k0 = 0; k0 < 1024; k0 += 64) {
    #pragma unroll
    for (int r = 0; r < 4; ++r) {
      int linear = r * 1024 + tid * 4;
      int nn = linear >> 6, kk = linear & 63;
      float4 av = *(const float4*)(A + (size_t)(bn + nn) * 1024 + k0 + kk);
      As[nn][kk+0] = av.x; As[nn][kk+1] = av.y; As[nn][kk+2] = av.z; As[nn][kk+3] = av.w;
      float4 xv = make_float4(0.f, 0.f, 0.f, 0.f);
      if (bm + nn < M) xv = *(const float4*)(X + (size_t)(bm + nn) * ldx + k0 + kk);
      Xs[nn][kk+0] = xv.x; Xs[nn][kk+1] = xv.y; Xs[nn][kk+2] = xv.z; Xs[nn][kk+3] = xv.w;
    }
    __syncthreads();
    #pragma unroll 16
    for (int kk = 0; kk < 64; ++kk) {
      float av[4], xv[4];
      #pragma unroll
      for (int u = 0; u < 4; ++u) { av[u] = As[tn*4+u][kk]; xv[u] = Xs[tm*4+u][kk]; }
      #pragma unroll
      for (int i = 0; i < 4; ++i)
        #pragma unroll
        for (int j = 0; j < 4; ++j) acc[i][j] += xv[i] * av[j];
    }
    __syncthreads();
  }
  #pragma unroll
  for (int i = 0; i < 4; ++i) {
    int m = bm + tm * 4 + i;
    if (m >= M) continue;
    #pragma unroll
    for (int j = 0; j < 4; ++j) {
      int n = bn + tn * 4 + j;
      float r = acc[i][j];
      if (b1) r += b1[n];
      if (b2) r += b2[n];
      Out[(size_t)m * ldo + n] = r;
    }
  }
}

__global__ void diag_k(const float* __restrict__ wh, const float* __restrict__ wht,
                       float* __restrict__ diag)
{
  int i = blockIdx.x * 256 + threadIdx.x;
  if (i < 2048) {
    int l = i >> 10, h = i & 1023;
    size_t idx = (size_t)l * 1048576 + (size_t)h * 1025;
    diag[i]        = wh[idx];
    diag[2048 + i] = wht[idx];
  }
}

__global__ __launch_bounds__(256) void phase1_l0_k(const float* __restrict__ XI0,
    float* __restrict__ tapeh, float* __restrict__ tapec, float* __restrict__ h0p1)
{
  int t = blockIdx.x;
  #pragma unroll
  for (int r = 0; r < 4; ++r) {
    int c = threadIdx.x + r * 256;
    float gi = XI0[t*4096 + c];
    float gg = XI0[t*4096 + 2048 + c];
    float go = XI0[t*4096 + 3072 + c];
    float cc = sigf(gi) * tanhf(gg);
    float hh = sigf(go) * tanhf(cc);
    tapeh[t*2048 + c] = hh;
    tapec[t*2048 + c] = cc;
    h0p1[t*1024 + c] = hh;
  }
}

__global__ __launch_bounds__(256) void phase1_l1_k(const float* __restrict__ G1,
    float* __restrict__ tapeh, float* __restrict__ tapec)
{
  int t = blockIdx.x;
  #pragma unroll
  for (int r = 0; r < 4; ++r) {
    int c = threadIdx.x + r * 256;
    float gi = G1[t*4096 + c];
    float gg = G1[t*4096 + 2048 + c];
    float go = G1[t*4096 + 3072 + c];
    float cc = sigf(gi) * tanhf(gg);
    float hh = sigf(go) * tanhf(cc);
    tapeh[t*2048 + 1024 + c] = hh;
    tapec[t*2048 + 1024 + c] = cc;
  }
}

__device__ __forceinline__ float red16(float p) {
  #pragma unroll
  for (int o = 8; o >= 1; o >>= 1) p += __shfl_xor(p, o, 16);
  return p;  // per-16-lane-group sum
}

// ---------------------------------------------------------------------------
// 2-level arrive + flag broadcast. Per group (stride 512 u32):
//   L1 counters: base[i*16], i=0..15 (8 WGs each, 64B apart)
//   L2 counter:  base[256]
//   flag:        base[320]  (generation: bootstrap=1, epoch t -> t-28)
// ---------------------------------------------------------------------------
__device__ __forceinline__ void arrive(unsigned* __restrict__ base, int gw) {
  asm volatile("s_waitcnt vmcnt(0)" ::: "memory");
  __syncthreads();
  if (threadIdx.x == 0) {
    unsigned o = __hip_atomic_fetch_add(&base[(gw >> 3) * 16], 1u,
                                        __ATOMIC_RELAXED, __HIP_MEMORY_SCOPE_AGENT);
    if (((o + 1) & 7u) == 0u) {
      unsigned o2 = __hip_atomic_fetch_add(&base[256], 1u,
                                           __ATOMIC_RELAXED, __HIP_MEMORY_SCOPE_AGENT);
      if (((o2 + 1) & 15u) == 0u)
        __hip_atomic_store(&base[320], (o2 + 1) >> 4,
                           __ATOMIC_RELAXED, __HIP_MEMORY_SCOPE_AGENT);
    }
  }
}

__device__ __forceinline__ void waitf(const unsigned* __restrict__ fOwn, unsigned tOwn,
                                      const unsigned* __restrict__ fOth, unsigned tOth) {
  if (threadIdx.x < 2) {
    const unsigned* fp = threadIdx.x ? fOth : fOwn;
    unsigned tgt = threadIdx.x ? tOth : tOwn;
    if (tgt) {
      while (__hip_atomic_load(fp, __ATOMIC_RELAXED, __HIP_MEMORY_SCOPE_AGENT) < tgt)
        __builtin_amdgcn_s_sleep(1);
    }
  }
  __syncthreads();
  asm volatile("" ::: "memory");
}

// ---------------------------------------------------------------------------
// Pipelined persistent scan. LW=0: 128 WGs, layer-0 recurrence, barrier group 0.
// LW=1: 128 WGs, layer-1, one step behind, consuming h0 via group-0 flag.
// ---------------------------------------------------------------------------
template <int LW>
__device__ __forceinline__ void run_group(
    const int gw,
    const float* __restrict__ wih, const float* __restrict__ whh,
    const float* __restrict__ bih, const float* __restrict__ bhh,
    const float* __restrict__ diag, const float* __restrict__ av,
    const float* __restrict__ XI0, const float* __restrict__ XA,
    const float* __restrict__ tapehG, const float* __restrict__ tapecG,
    const float* __restrict__ Pg,
    float* __restrict__ scoresG, float* __restrict__ prevh,
    float* __restrict__ h0cur, float* __restrict__ h1cur,
    float* __restrict__ outp, unsigned* __restrict__ bar,
    float* tape, float* hA, float* hB, float* Pl, float* tc,
    float* sc, float* aw, float* gls, float* ihs, float* ncs,
    float* bsum, float* sred)
{
  const int tid = threadIdx.x;
  const int rid = tid >> 4, sub = tid & 15;       // 32 row-slots x 16 lanes
  const int cell = (gw << 3) + (rid & 7);
  const int row = ((rid >> 3) << 10) + cell;      // gate*1024 + cell
  const bool isScore = (gw < 29);
  const int h2 = tid * 2;

  unsigned* __restrict__ barOwn = bar + (LW ? 512 : 0);
  const unsigned* __restrict__ fOwn = barOwn + 320;
  const unsigned* __restrict__ fOth = bar + (LW ? 0 : 512) + 320;

  // ---- one-time init: weights -> VGPRs, P/tape/tc -> LDS ----
  float wA[64];
  float wB[LW ? 64 : 1];
  {
    const float* pa = whh + (size_t)LW * LSTRIDE + (size_t)row * 1024 + sub * 64;
    #pragma unroll
    for (int i = 0; i < 16; ++i) {
      float4 v = ((const float4*)pa)[i];
      wA[4*i] = v.x; wA[4*i+1] = v.y; wA[4*i+2] = v.z; wA[4*i+3] = v.w;
    }
    if (LW) {
      const float* pb = wih + LSTRIDE + (size_t)row * 1024 + sub * 64;
      #pragma unroll
      for (int i = 0; i < 16; ++i) {
        float4 v = ((const float4*)pb)[i];
        wB[4*i] = v.x; wB[4*i+1] = v.y; wB[4*i+2] = v.z; wB[4*i+3] = v.w;
      }
    }
  }
  if (LW && sub == 0) bsum[rid] = bih[4096 + row] + bhh[4096 + row];
  for (int k = tid; k < 960; k += 512) {
    int s = k >> 5, r = k & 31;
    int rr = ((r >> 3) << 10) + (gw << 3) + (r & 7);
    Pl[s * 34 + r] = Pg[s * 4096 + rr];
  }
  for (int k = tid; k < 240; k += 512) {
    int s = k >> 3, c = k & 7;
    tc[s * 9 + c] = tapecG[s * 2048 + LW * 1024 + (gw << 3) + c];
  }
  if (isScore) {
    for (int k = tid; k < 7680; k += 512) {
      int s = k >> 8, off = (k & 255) << 2;
      *(float4*)&tape[s * 1024 + off] =
          *(const float4*)&tapehG[s * 2048 + LW * 1024 + off];
    }
  }
  const float ddx = diag[LW*1024 + h2],        ddy = diag[LW*1024 + h2 + 1];
  const float ttx = diag[2048 + LW*1024 + h2], tty = diag[2048 + LW*1024 + h2 + 1];
  const float vvx = av[LW*1024 + h2],          vvy = av[LW*1024 + h2 + 1];
  __syncthreads();

  // ---- bootstrap: scores(t=30) for all 30 slots (prev_h = 0) ----
  if (isScore) {
    for (int s = gw; s < 30; s += 29) {
      float2 xa = *(const float2*)&XA[(size_t)30 * 2048 + LW * 1024 + h2];
      float part = vvx * tanhf(ddx * tape[s*1024 + h2] + xa.x)
                 + vvy * tanhf(ddy * tape[s*1024 + h2 + 1] + xa.y);
      #pragma unroll
      for (int o = 32; o >= 1; o >>= 1) part += __shfl_xor(part, o, 64);
      if ((tid & 63) == 0) sred[tid >> 6] = part;
      __syncthreads();
      if (tid == 0) {
        float tot = 0.f;
        #pragma unroll
        for (int i = 0; i < 8; ++i) tot += sred[i];
        cstore(&scoresG[LW * 32 + s], tot);
      }
      __syncthreads();
    }
  }
  arrive(barOwn, gw);   // flag -> 1

  for (int t = 30; t < 512; ++t) {
    // ---- wait: own flag + cross-group flag ----
    unsigned tOwn = (unsigned)(t - 29);
    unsigned tOth;
    if (LW == 0) tOth = (t >= 33) ? (unsigned)(t - 32) : 0u;   // backpressure
    else         tOth = (unsigned)(t - 28);                    // h0(t) ready
    waitf(fOwn, tOwn, fOth, tOth);

    const int tmod = t % 30;
    const int pslot = (tmod == 0) ? 29 : tmod - 1;

    // ---- epoch-start loads (all independent, issued together) ----
    if (tid < 30) sc[tid] = cload(&scoresG[(t & 1) * 64 + LW * 32 + tid]);
    float2 hva, hvb = make_float2(0.f, 0.f), ph = make_float2(0.f, 0.f),
           xan = make_float2(0.f, 0.f);
    if (LW == 0) {
      hva = cload2(&h0cur[(size_t)((t - 1) & 3) * 1024 + h2]);   // h0(t-1)
    } else {
      hva = cload2(&h0cur[(size_t)(t & 3) * 1024 + h2]);         // h0(t)
      hvb = cload2(&h1cur[((t - 1) & 1) * 1024 + h2]);           // h1(t-1)
    }
    if (t > 30) {
      ph  = cload2(&prevh[((t - 1) & 1) * 2048 + LW * 1024 + h2]);
      xan = *(const float2*)&XA[(size_t)t * 2048 + LW * 1024 + h2];
    }
    float xi = 0.f;
    if (LW == 0 && sub == 0) xi = XI0[(size_t)t * 4096 + row];
    {
      int o = (h2 >> 6) * 66 + (h2 & 63);
      hA[o] = hva.x; hA[o + 1] = hva.y;
      if (LW) { hB[o] = hvb.x; hB[o + 1] = hvb.y; }
    }
    __syncthreads();

    // ---- new-slot score partial + P-col matvec + tape refresh ----
    if (t > 30) {
      float2 hn = LW ? hvb : hva;                 // own-layer h(t-1)
      float np = vvx * tanhf(ddx * hn.x + xan.x + ttx * ph.x)
               + vvy * tanhf(ddy * hn.y + xan.y + tty * ph.y);
      #pragma unroll
      for (int o = 32; o >= 1; o >>= 1) np += __shfl_xor(np, o, 64);
      if ((tid & 63) == 0) sred[tid >> 6] = np;
      const float* hbufP = LW ? hB : hA;
      float pc = 0.f;
      #pragma unroll
      for (int i = 0; i < 64; ++i) pc += wA[i] * hbufP[sub * 66 + i];
      pc = red16(pc);
      if (sub == 0) Pl[pslot * 34 + rid] = pc;
      if (isScore) {
        tape[pslot * 1024 + h2]     = hn.x;
        tape[pslot * 1024 + h2 + 1] = hn.y;
      }
    }
    if (LW) {  // w_ih1 @ h0(t), every epoch
      float ih = 0.f;
      #pragma unroll
      for (int i = 0; i < 64; ++i) ih += wB[i] * hA[sub * 66 + i];
      ih = red16(ih);
      if (sub == 0) ihs[rid] = ih + bsum[rid];
    }
    __syncthreads();

    // ---- softmax (wave 0, new-slot score folded in) ----
    if (tid < 32) {
      float npv = 0.f;
      if (t > 30) {
        float x = (tid < 8) ? sred[tid] : 0.f;
        #pragma unroll
        for (int o = 4; o >= 1; o >>= 1) x += __shfl_xor(x, o, 8);
        npv = __shfl(x, 0, 32);
      }
      float v = (tid < 30) ? sc[tid] : -1e30f;
      if (t > 30 && tid == pslot) v = npv;
      float m = v;
      #pragma unroll
      for (int o = 16; o >= 1; o >>= 1) m = fmaxf(m, __shfl_xor(m, o, 32));
      float e = (tid < 30) ? expf(v - m) : 0.f;
      float sm = e;
      #pragma unroll
      for (int o = 16; o >= 1; o >>= 1) sm += __shfl_xor(sm, o, 32);
      aw[tid] = e / sm;
    }
    __syncthreads();

    // ---- gates (alpha-weighted P) + c-tape sums ----
    {
      float p = aw[sub] * Pl[sub * 34 + rid];
      if (sub < 14) p += aw[sub + 16] * Pl[(sub + 16) * 34 + rid];
      p = red16(p);
      if (sub == 0) gls[rid] = p + (LW ? ihs[rid] : xi);
      if (rid < 8) {
        float pn = aw[sub] * tc[sub * 9 + rid];
        if (sub < 14) pn += aw[sub + 16] * tc[(sub + 16) * 9 + rid];
        pn = red16(pn);
        if (sub == 0) ncs[rid] = pn;
      }
    }
    __syncthreads();

    // ---- LSTM cell + publish ----
    if (tid < 8) {
      float gi = gls[tid], gf = gls[8 + tid], gg = gls[16 + tid], go = gls[24 + tid];
      float cv = sigf(gf) * ncs[tid] + sigf(gi) * tanhf(gg);
      float hv = sigf(go) * tanhf(cv);
      if (LW == 0) {
        cstore(&h0cur[(size_t)(t & 3) * 1024 + (gw << 3) + tid], hv);
      } else {
        outp[(size_t)(t - 30) * 1024 + (gw << 3) + tid] = hv;
        cstore(&h1cur[(t & 1) * 1024 + (gw << 3) + tid], hv);
      }
      tc[tmod * 9 + tid] = cv;
    }

    // ---- score WGs: old-slot scores for t+1 + prevh(t) ----
    if (isScore && t < 511) {
      int ss = tmod + 1 + gw; if (ss >= 30) ss -= 30;
      float ax = 0.f, ay = 0.f;
      #pragma unroll
      for (int s = 0; s < 30; ++s) {
        float as = aw[s];
        ax += as * tape[s * 1024 + h2];
        ay += as * tape[s * 1024 + h2 + 1];
      }
      if (gw == 0) cstore2(&prevh[(t & 1) * 2048 + LW * 1024 + h2],
                           make_float2(ax, ay));
      float2 xa2 = *(const float2*)&XA[(size_t)(t + 1) * 2048 + LW * 1024 + h2];
      float part = vvx * tanhf(ddx * tape[ss * 1024 + h2] + xa2.x + ttx * ax)
                 + vvy * tanhf(ddy * tape[ss * 1024 + h2 + 1] + xa2.y + tty * ay);
      #pragma unroll
      for (int o = 32; o >= 1; o >>= 1) part += __shfl_xor(part, o, 64);
      if ((tid & 63) == 0) sred[tid >> 6] = part;
      __syncthreads();
      if (tid == 0) {
        float tot = 0.f;
        #pragma unroll
        for (int i = 0; i < 8; ++i) tot += sred[i];
        cstore(&scoresG[((t + 1) & 1) * 64 + LW * 32 + ss], tot);
      }
    }

    arrive(barOwn, gw);   // flag -> t-28
  }
}

__global__ __launch_bounds__(512, 2) void scan_fused(
    const float* __restrict__ wih, const float* __restrict__ whh,
    const float* __restrict__ bih, const float* __restrict__ bhh,
    const float* __restrict__ diag, const float* __restrict__ av,
    const float* __restrict__ XI0, const float* __restrict__ XA,
    const float* __restrict__ tapehG, const float* __restrict__ tapecG,
    const float* __restrict__ P0g, const float* __restrict__ P1g,
    float* __restrict__ scoresG, float* __restrict__ prevh,
    float* __restrict__ h0cur, float* __restrict__ h1cur,
    float* __restrict__ outp, unsigned* __restrict__ bar)
{
  __shared__ float tape[30 * 1024];
  __shared__ float hA[16 * 66], hB[16 * 66];
  __shared__ float Pl[30 * 34];
  __shared__ float tc[30 * 9];
  __shared__ float sc[32], aw[32], gls[32], ihs[32], ncs[8], bsum[32], sred[8];
  if (blockIdx.x < 128)
    run_group<0>(blockIdx.x, wih, whh, bih, bhh, diag, av, XI0, XA, tapehG, tapecG,
                 P0g, scoresG, prevh, h0cur, h1cur, outp, bar,
                 tape, hA, hB, Pl, tc, sc, aw, gls, ihs, ncs, bsum, sred);
  else
    run_group<1>(blockIdx.x - 128, wih, whh, bih, bhh, diag, av, XI0, XA, tapehG, tapecG,
                 P1g, scoresG, prevh, h0cur, h1cur, outp, bar,
                 tape, hA, hB, Pl, tc, sc, aw, gls, ihs, ncs, bsum, sred);
}

// ---------------------------------------------------------------------------
extern "C" void kernel_launch(void* const* d_in, const int* in_sizes, int n_in,
                              void* d_out, int out_size, void* d_ws, size_t ws_size,
                              hipStream_t stream) {
  (void)in_sizes; (void)n_in; (void)out_size; (void)ws_size;
  const float* xs    = (const float*)d_in[0];
  const float* w_ih  = (const float*)d_in[1];
  const float* w_hh  = (const float*)d_in[2];
  const float* b_ih  = (const float*)d_in[3];
  const float* b_hh  = (const float*)d_in[4];
  const float* a_wh  = (const float*)d_in[5];
  const float* a_wx  = (const float*)d_in[6];
  const float* a_wht = (const float*)d_in[7];
  const float* a_v   = (const float*)d_in[8];
  float* outp = (float*)d_out;

  float* ws     = (float*)d_ws;
  float* XI0    = ws;                      // 512*4096
  float* XA     = XI0    + 512 * 4096;     // 512*2048
  float* tapehG = XA     + 512 * 2048;     // 30*2048
  float* tapecG = tapehG + 30 * 2048;      // 30*2048
  float* P0g    = tapecG + 30 * 2048;      // 30*4096
  float* P1g    = P0g    + 30 * 4096;      // 30*4096
  float* diag   = P1g    + 30 * 4096;      // 4096
  float* scor   = diag   + 4096;           // 2*64
  float* prevh  = scor   + 128;            // 2*2048
  float* h0cur  = prevh  + 4096;           // 4*1024 (depth-4)
  float* h1cur  = h0cur  + 4096;           // 2*1024
  float* h0p1   = h1cur  + 2048;           // 30*1024
  float* G1b    = h0p1   + 30 * 1024;      // 30*4096
  unsigned* bar = (unsigned*)(G1b + 30 * 4096);  // 2 groups x 512 u32

  hipMemsetAsync(outp + (size_t)482 * 1024, 0, 30 * 1024 * sizeof(float), stream);
  hipMemsetAsync(bar, 0, 4096, stream);

  diag_k<<<8, 256, 0, stream>>>(a_wh, a_wht, diag);

  gemm_nt<<<dim3(64, 8), 256, 0, stream>>>(w_ih, xs, XI0, b_ih, b_hh, 512, 1024, 4096);
  gemm_nt<<<dim3(16, 8), 256, 0, stream>>>(a_wx, xs, XA, nullptr, nullptr, 512, 1024, 2048);
  gemm_nt<<<dim3(16, 8), 256, 0, stream>>>(a_wx + LSTRIDE / 4, xs, XA + 1024, nullptr, nullptr, 512, 1024, 2048);

  phase1_l0_k<<<30, 256, 0, stream>>>(XI0, tapehG, tapecG, h0p1);
  gemm_nt<<<dim3(64, 1), 256, 0, stream>>>(w_ih + LSTRIDE, h0p1, G1b, b_ih + 4096, b_hh + 4096, 30, 1024, 4096);
  phase1_l1_k<<<30, 256, 0, stream>>>(G1b, tapehG, tapecG);

  gemm_nt<<<dim3(64, 1), 256, 0, stream>>>(w_hh, tapehG, P0g, nullptr, nullptr, 30, 2048, 4096);
  gemm_nt<<<dim3(64, 1), 256, 0, stream>>>(w_hh + LSTRIDE, tapehG + 1024, P1g, nullptr, nullptr, 30, 2048, 4096);

  const float* wihp = w_ih;
  const float* whhp = w_hh;
  const float* bihp = b_ih;
  const float* bhhp = b_hh;
  void* kargs[] = {
    (void*)&wihp, (void*)&whhp, (void*)&bihp, (void*)&bhhp,
    (void*)&diag, (void*)&a_v,  (void*)&XI0,  (void*)&XA,
    (void*)&tapehG, (void*)&tapecG, (void*)&P0g, (void*)&P1g,
    (void*)&scor, (void*)&prevh, (void*)&h0cur, (void*)&h1cur,
    (void*)&outp, (void*)&bar
  };
  hipLaunchCooperativeKernel((void*)scan_fused, dim3(256), dim3(512), kargs, 0, stream);
}